// Round 3
// baseline (295.433 us; speedup 1.0000x reference)
//
#include <hip/hip_runtime.h>
#include <math.h>

#define BN_SCALE 0.99999500003749967f
#define RRELU_SLOPE 0.22916666666666666f

static __device__ __forceinline__ float leaky(float v) { return v > 0.f ? v : 0.01f * v; }

typedef __attribute__((ext_vector_type(8))) short bf16x8;
typedef __attribute__((ext_vector_type(4))) float f32x4;

static __device__ __forceinline__ unsigned short f2bf(float f) {
  unsigned u = __builtin_bit_cast(unsigned, f);
  u = (u + 0x7FFFu + ((u >> 16) & 1u)) >> 16;
  return (unsigned short)u;
}

// ---------------------------------------------------------------------------
// setup: conv frags, Wgagb B-frags, folded biases. 75 blocks x 256.
// (w1 transpose ELIMINATED: c1 now reads cw1 directly in fp32.)
// ---------------------------------------------------------------------------
__global__ __launch_bounds__(256) void setup_kernel(
    const float* __restrict__ w2c, const float* __restrict__ g2,
    const float* __restrict__ w3c, const float* __restrict__ g3,
    const float* __restrict__ fcw, const float* __restrict__ fcb,
    const float* __restrict__ w1,  const float* __restrict__ b1,
    unsigned short* __restrict__ w2frag,
    unsigned short* __restrict__ w3frag,
    unsigned short* __restrict__ bfragGG,
    float* __restrict__ bgagb)
{
  const int item = blockIdx.x * 256 + threadIdx.x;
  if (item < 512) {                      // conv2 A-frags
    const int tl = item >> 6, lane = item & 63;
    const int mt = tl >> 1, kc = tl & 1;
    const int lr = lane & 15, quad = lane >> 4;
    const int c = mt * 16 + lr;
    const float gs = g2[c] * BN_SCALE;
#pragma unroll
    for (int j = 0; j < 8; ++j) {
      const int k = quad * 8 + j;
      float v;
      if (kc == 0) { const int tap = k >> 4, ci = k & 15; v = w2c[c * 48 + ci * 3 + tap] * gs; }
      else         { v = (k < 16) ? w2c[c * 48 + k * 3 + 2] * gs : 0.f; }
      w2frag[item * 8 + j] = f2bf(v);
    }
  } else if (item < 1664) {              // conv3 A-frags
    const int it = item - 512;
    const int tl = it >> 6, lane = it & 63;
    const int mt = tl / 3, tap = tl - mt * 3;
    const int lr = lane & 15, quad = lane >> 4;
    const int c = mt * 16 + lr;
    const float gs = g3[c] * BN_SCALE;
#pragma unroll
    for (int j = 0; j < 8; ++j) {
      const int ci = quad * 8 + j;
      w3frag[it * 8 + j] = f2bf(w3c[c * 96 + ci * 3 + tap] * gs);
    }
  } else if (item < 19072) {             // Wgagb B-frags
    const int it = item - 1664;
    const int chunk = it >> 8;
    const int rem = it & 255;
    const int nt = rem >> 6;
    const int lane = rem & 63;
    const int lr = lane & 15, quad = lane >> 4;
    const int n = nt * 16 + lr;
    const int off = (n >= 32) ? 32 : 0;
    const int nj = n & 31;
    float w1col[32];
#pragma unroll 8
    for (int q = 0; q < 32; ++q) w1col[q] = w1[(q + off) * 32 + nj];
#pragma unroll
    for (int j = 0; j < 8; ++j) {
      const int k = chunk * 32 + quad * 8 + j;
      float v = 0.f;
      if (k < 2160) {
        const float* fr = fcw + (size_t)k * 32;
#pragma unroll 8
        for (int q = 0; q < 32; ++q) v = fmaf(fr[q], w1col[q], v);
      }
      bfragGG[(size_t)it * 8 + j] = f2bf(v);
    }
  } else if (item < 19136) {             // folded biases
    const int n = item - 19072;
    const int off = (n >= 32) ? 32 : 0;
    const int nj = n & 31;
    float s = (n < 32) ? b1[nj] : 0.f;
    for (int q = 0; q < 32; ++q) s = fmaf(fcb[q], w1[(q + off) * 32 + nj], s);
    bgagb[n] = s;
  }
}

// ---------------------------------------------------------------------------
// fe: wave-autonomous (R0 structure; R1's 2-wave split regressed: barriers +
// duplicated setup outweighed the never-materialized occupancy gain). s2t
// OVERLAYS s1t (safe: tile nt reads rows 16nt..16nt+17 before writing rows
// <=16nt+15; later tiles read only higher rows; DS pipe in-order per wave).
// Kept from R1: leaky applied AFTER pool-max (bit-exact, monotone).
// Arena 6912 B per wave -> 11 blocks (22 waves)/CU.
// ---------------------------------------------------------------------------
__global__ __launch_bounds__(128) void fe_kernel(
    const float* __restrict__ x,
    const float* __restrict__ w1c, const float* __restrict__ b1c,
    const float* __restrict__ g1,  const float* __restrict__ bb1,
    const float* __restrict__ b2c, const float* __restrict__ g2, const float* __restrict__ bb2,
    const float* __restrict__ b3c, const float* __restrict__ g3, const float* __restrict__ bb3,
    const unsigned short* __restrict__ w2frag,
    const unsigned short* __restrict__ w3frag,
    unsigned short* __restrict__ act3)
{
  __shared__ __align__(16) char smem[2 * 6912];
  const int t = threadIdx.x;
  const int wv = t >> 6, lane = t & 63, quad = lane >> 4, lr = lane & 15;
  const int n = blockIdx.x * 2 + wv;

  char* A = smem + wv * 6912;
  unsigned short* buf = (unsigned short*)A;   // s1t: 194r x 16sh / s2t: 98r x 32sh (overlaid)
  float* be2 = (float*)(A + 6272);            // 64
  float* be3 = (float*)(A + 6528);            // 96

  bf16x8 a2[4][2];
#pragma unroll
  for (int mt = 0; mt < 4; ++mt)
#pragma unroll
    for (int kc = 0; kc < 2; ++kc)
      a2[mt][kc] = *(const bf16x8*)(w2frag + ((mt * 2 + kc) * 64 + lane) * 8);

  be2[lane] = b2c[lane] * (g2[lane] * BN_SCALE) + bb2[lane];
  be3[lane] = b3c[lane] * (g3[lane] * BN_SCALE) + bb3[lane];
  if (lane < 32) be3[64 + lane] = b3c[64 + lane] * (g3[64 + lane] * BN_SCALE) + bb3[64 + lane];
  ((unsigned*)buf)[1488 + lane] = 0;          // s1t pad rows 186..193

  const int cp = lane & 7;
  float u[4][3], bbr[4];
#pragma unroll
  for (int d = 0; d < 4; ++d) {
    const int c = cp * 4 + d;
    const float gs = g1[c] * BN_SCALE;
    u[d][0] = w1c[c * 3 + 0] * gs;
    u[d][1] = w1c[c * 3 + 1] * gs;
    u[d][2] = w1c[c * 3 + 2] * gs;
    bbr[d] = b1c[c] * gs + bb1[c];
  }

  // ---- stage 1: conv1+bn+pool+leaky -> buf rows 0..185 (16sh stride) ----
  // leaky is monotone: apply once AFTER the 2x2 pool max (bit-identical).
  const float* xr = x + (size_t)n * 375;
  for (int o = lane; o < 1488; o += 64) {
    const int l = o >> 3;
    const int p = 2 * l;
    const float x0 = xr[p], x1 = xr[p + 1], x2 = xr[p + 2], x3 = xr[p + 3];
    unsigned pk = 0;
#pragma unroll
    for (int uu = 0; uu < 2; ++uu) {
      float m = -3.4e38f;
#pragma unroll
      for (int dc = 0; dc < 2; ++dc) {
        const int d = uu * 2 + dc;
        const float v0 = fmaf(x0, u[d][0], fmaf(x1, u[d][1], fmaf(x2, u[d][2], bbr[d])));
        const float v1 = fmaf(x1, u[d][0], fmaf(x2, u[d][1], fmaf(x3, u[d][2], bbr[d])));
        m = fmaxf(m, fmaxf(v0, v1));
      }
      pk |= (unsigned)f2bf(leaky(m)) << (16 * uu);
    }
    ((unsigned*)buf)[l * 8 + cp] = pk;
  }

  float be2r[4][4];
#pragma unroll
  for (int mt = 0; mt < 4; ++mt)
#pragma unroll
    for (int r = 0; r < 4; ++r) be2r[mt][r] = be2[mt * 16 + quad * 4 + r];

  // ---- conv2: 12 n-tiles; reads s1t rows, writes s2t rows (overlaid) ----
#pragma unroll 2
  for (int nt = 0; nt < 12; ++nt) {
    const int nrow = nt * 16 + lr;
    bf16x8 b0 = *(const bf16x8*)(buf + (nrow + (quad >> 1)) * 16 + (quad & 1) * 8);
    bf16x8 b1 = *(const bf16x8*)(buf + (nrow + 2) * 16 + (quad & 1) * 8);
    f32x4 acc[4];
#pragma unroll
    for (int mt = 0; mt < 4; ++mt)
#pragma unroll
      for (int r = 0; r < 4; ++r) acc[mt][r] = be2r[mt][r];
#pragma unroll
    for (int mt = 0; mt < 4; ++mt)
      acc[mt] = __builtin_amdgcn_mfma_f32_16x16x32_bf16(a2[mt][0], b0, acc[mt], 0, 0, 0);
#pragma unroll
    for (int mt = 0; mt < 4; ++mt)
      acc[mt] = __builtin_amdgcn_mfma_f32_16x16x32_bf16(a2[mt][1], b1, acc[mt], 0, 0, 0);
#pragma unroll
    for (int mt = 0; mt < 4; ++mt) {
      float o[4];
#pragma unroll
      for (int r = 0; r < 4; ++r)
        o[r] = fmaxf(acc[mt][r], __shfl_xor(acc[mt][r], 1));
      if ((lr & 1) == 0) {
        const int np = nrow >> 1;
        if (np <= 91) {
          const float m0 = leaky(fmaxf(o[0], o[1]));
          const float m1 = leaky(fmaxf(o[2], o[3]));
          const unsigned pk = (unsigned)f2bf(m0) | ((unsigned)f2bf(m1) << 16);
          ((unsigned*)buf)[np * 16 + mt * 4 + quad] = pk;
        }
      }
    }
  }

  // ---- zero s2t pad rows 92..97 (safe: conv2 done with s1t tail) ----
  ((unsigned*)buf)[1472 + lane] = 0;
  if (lane < 32) ((unsigned*)buf)[1536 + lane] = 0;

  // ---- conv3: 6x6 tiles x 3 tap-MFMAs; epilogue -> act3 (global) ----
  unsigned short* actr = act3 + (size_t)n * 2176;
  for (int mt = 0; mt < 6; ++mt) {
    bf16x8 a3[3];
#pragma unroll
    for (int tap = 0; tap < 3; ++tap)
      a3[tap] = *(const bf16x8*)(w3frag + ((mt * 3 + tap) * 64 + lane) * 8);
    float be3r[4];
#pragma unroll
    for (int r = 0; r < 4; ++r) be3r[r] = be3[mt * 16 + quad * 4 + r];
#pragma unroll
    for (int nt = 0; nt < 6; ++nt) {
      const int nrow = nt * 16 + lr;
      f32x4 acc;
#pragma unroll
      for (int r = 0; r < 4; ++r) acc[r] = be3r[r];
#pragma unroll
      for (int tap = 0; tap < 3; ++tap) {
        bf16x8 b = *(const bf16x8*)(buf + (nrow + tap) * 32 + quad * 8);
        acc = __builtin_amdgcn_mfma_f32_16x16x32_bf16(a3[tap], b, acc, 0, 0, 0);
      }
      float o[4];
#pragma unroll
      for (int r = 0; r < 4; ++r)
        o[r] = fmaxf(acc[r], __shfl_xor(acc[r], 1));
      if ((lr & 1) == 0) {
        const int np = nrow >> 1;
        if (np <= 44) {
          const int mp = mt * 8 + quad * 2;
          actr[mp * 45 + np] = f2bf(leaky(fmaxf(o[0], o[1])));
          actr[(mp + 1) * 45 + np] = f2bf(leaky(fmaxf(o[2], o[3])));
        }
      }
    }
  }
  if (lane < 16) actr[2160 + lane] = 0;
}

// ---------------------------------------------------------------------------
// gagb: 254 blocks x 16 rows; 4 waves split K (17 chunks each); LDS reduce.
// ---------------------------------------------------------------------------
__global__ __launch_bounds__(256) void gagb_kernel(
    const unsigned short* __restrict__ act3,
    const unsigned short* __restrict__ bfragGG,
    const float* __restrict__ bgagb,
    float* __restrict__ Ga, float* __restrict__ Gb)
{
  __shared__ f32x4 sred[3][4][64];
  const int t = threadIdx.x;
  const int wv = t >> 6, lane = t & 63, quad = lane >> 4, lr = lane & 15;
  const int m0 = blockIdx.x * 16;
  const int arow = min(m0 + lr, 4049);

  f32x4 acc[4] = {};
  const int c0 = wv * 17;
  for (int chunk = c0; chunk < c0 + 17; ++chunk) {
    const bf16x8 a = *(const bf16x8*)(act3 + (size_t)arow * 2176 + chunk * 32 + quad * 8);
#pragma unroll
    for (int nt = 0; nt < 4; ++nt) {
      const bf16x8 b = *(const bf16x8*)(bfragGG + ((size_t)(chunk * 4 + nt) * 64 + lane) * 8);
      acc[nt] = __builtin_amdgcn_mfma_f32_16x16x32_bf16(a, b, acc[nt], 0, 0, 0);
    }
  }
  if (wv > 0) {
#pragma unroll
    for (int nt = 0; nt < 4; ++nt) sred[wv - 1][nt][lane] = acc[nt];
  }
  __syncthreads();
  if (wv == 0) {
#pragma unroll
    for (int nt = 0; nt < 4; ++nt) {
      f32x4 s = acc[nt];
#pragma unroll
      for (int q = 0; q < 3; ++q) {
        const f32x4 o = sred[q][nt][lane];
#pragma unroll
        for (int r = 0; r < 4; ++r) s[r] += o[r];
      }
      const int col = nt * 16 + lr;
      const float bias = bgagb[col];
#pragma unroll
      for (int r = 0; r < 4; ++r) {
        const int row = m0 + quad * 4 + r;
        if (row < 4050) {
          const float v = s[r] + bias;
          if (col < 32) Ga[row * 32 + col] = v;
          else          Gb[row * 32 + (col - 32)] = v;
        }
      }
    }
  }
}

// ---------------------------------------------------------------------------
// sim: 960 blocks = 30 subjects x 32 chunks; writes f32 subjectsT[p][b]
// (k-major rows of 32 floats so c1 can broadcast-read 30 subjects per k).
// ---------------------------------------------------------------------------
__global__ __launch_bounds__(256) void sim_kernel(
    const float* __restrict__ Ga, const float* __restrict__ Gb,
    const float* __restrict__ w2, const float* __restrict__ b2,
    const float* __restrict__ w3, const float* __restrict__ b3,
    const float* __restrict__ w4, const float* __restrict__ b4,
    float* __restrict__ subjectsT)
{
  __shared__ float sGa[135 * 36];
  __shared__ float sGb[135 * 36];
  __shared__ float sw2[512], sw3[128], sw4[8];
  __shared__ float sb2[16], sb3[8], sb4v[1];

  const int t = threadIdx.x;
  const int b = blockIdx.x >> 5;
  const int c = blockIdx.x & 31;

  for (int i = t; i < 4320; i += 256) {
    const int r = i >> 5, col = i & 31;
    sGa[r * 36 + col] = Ga[b * 4320 + i];
    sGb[r * 36 + col] = Gb[b * 4320 + i];
  }
  for (int i = t; i < 512; i += 256) sw2[i] = w2[i];
  if (t < 128) sw3[t] = w3[t];
  if (t < 8) sw4[t] = w4[t];
  if (t < 16) sb2[t] = b2[t];
  if (t < 8) sb3[t] = b3[t];
  if (t == 0) sb4v[0] = b4[0];
  __syncthreads();

  const int pend = min(9045, (c + 1) * 283);
  for (int p = c * 283 + t; p < pend; p += 256) {
    int i = (int)((269.0f - sqrtf((float)(72361 - 8 * p))) * 0.5f);
    i = max(0, min(133, i));
    while (134 * (i + 1) - ((i + 1) * i) / 2 <= p) ++i;
    while (134 * i - (i * (i - 1)) / 2 > p) --i;
    const int j = i + 1 + (p - (134 * i - (i * (i - 1)) / 2));

    float h1[32];
#pragma unroll
    for (int q = 0; q < 8; ++q) {
      const float4 va = *(const float4*)(&sGa[i * 36 + 4 * q]);
      const float4 vb = *(const float4*)(&sGb[j * 36 + 4 * q]);
      h1[4 * q + 0] = fmaxf(va.x + vb.x, 0.f);
      h1[4 * q + 1] = fmaxf(va.y + vb.y, 0.f);
      h1[4 * q + 2] = fmaxf(va.z + vb.z, 0.f);
      h1[4 * q + 3] = fmaxf(va.w + vb.w, 0.f);
    }

    float h2[16];
#pragma unroll
    for (int jj = 0; jj < 16; ++jj) h2[jj] = sb2[jj];
#pragma unroll 8
    for (int ii = 0; ii < 32; ++ii) {
      const float av = h1[ii];
      const float4* wr = reinterpret_cast<const float4*>(&sw2[ii * 16]);
#pragma unroll
      for (int r = 0; r < 4; ++r) {
        float4 w = wr[r];
        h2[4 * r + 0] = fmaf(av, w.x, h2[4 * r + 0]);
        h2[4 * r + 1] = fmaf(av, w.y, h2[4 * r + 1]);
        h2[4 * r + 2] = fmaf(av, w.z, h2[4 * r + 2]);
        h2[4 * r + 3] = fmaf(av, w.w, h2[4 * r + 3]);
      }
    }
#pragma unroll
    for (int jj = 0; jj < 16; ++jj) h2[jj] = fmaxf(h2[jj], 0.f);

    float h3[8];
#pragma unroll
    for (int jj = 0; jj < 8; ++jj) h3[jj] = sb3[jj];
#pragma unroll
    for (int ii = 0; ii < 16; ++ii) {
      const float av = h2[ii];
      const float4* wr = reinterpret_cast<const float4*>(&sw3[ii * 8]);
#pragma unroll
      for (int r = 0; r < 2; ++r) {
        float4 w = wr[r];
        h3[4 * r + 0] = fmaf(av, w.x, h3[4 * r + 0]);
        h3[4 * r + 1] = fmaf(av, w.y, h3[4 * r + 1]);
        h3[4 * r + 2] = fmaf(av, w.z, h3[4 * r + 2]);
        h3[4 * r + 3] = fmaf(av, w.w, h3[4 * r + 3]);
      }
    }
#pragma unroll
    for (int jj = 0; jj < 8; ++jj) h3[jj] = fmaxf(h3[jj], 0.f);

    float z = sb4v[0];
#pragma unroll
    for (int ii = 0; ii < 8; ++ii) z = fmaf(h3[ii], sw4[ii], z);

    const float az = fabsf(z);
    const float e = __expf(-2.f * az);
    const float rr = (1.f - e) / (1.f + e);
    const float val = copysignf(rr, z);

    subjectsT[(size_t)p * 32 + b] = val;
  }
}

// ---------------------------------------------------------------------------
// c1_direct: C(30x1024) = subjectsT^T @ cw1, fp32, NO transpose of cw1.
// 512 blocks = 8 colgroups(128) x 64 kgroups(142, split 2 halves of 71 per
// block). k is wave-uniform -> subjectsT row reads are broadcast; cw1 row
// reads are fully coalesced (128 consecutive cols). Writes the same part
// layout as before so tail_a is unchanged.
// ---------------------------------------------------------------------------
__global__ __launch_bounds__(256) void c1_kernel(
    const float* __restrict__ subjectsT,
    const float* __restrict__ cw1,
    float* __restrict__ part)
{
  __shared__ float sred[128 * 30];
  const int t = threadIdx.x;
  const int cg = blockIdx.x & 7;
  const int kg = blockIdx.x >> 3;
  const int col = cg * 128 + (t & 127);
  const int ksub = t >> 7;
  const int k0 = kg * 142 + ksub * 71;
  const int kend = min(9045, k0 + 71);

  float acc[30];
#pragma unroll
  for (int m = 0; m < 30; ++m) acc[m] = 0.f;

  for (int k = k0; k < kend; ++k) {
    const float w = cw1[(size_t)k * 1024 + col];
    const float* sr = subjectsT + (size_t)k * 32;
    const float4 s0 = *(const float4*)(sr + 0);
    const float4 s1 = *(const float4*)(sr + 4);
    const float4 s2 = *(const float4*)(sr + 8);
    const float4 s3 = *(const float4*)(sr + 12);
    const float4 s4 = *(const float4*)(sr + 16);
    const float4 s5 = *(const float4*)(sr + 20);
    const float4 s6 = *(const float4*)(sr + 24);
    const float2 s7 = *(const float2*)(sr + 28);
    acc[0]  = fmaf(s0.x, w, acc[0]);  acc[1]  = fmaf(s0.y, w, acc[1]);
    acc[2]  = fmaf(s0.z, w, acc[2]);  acc[3]  = fmaf(s0.w, w, acc[3]);
    acc[4]  = fmaf(s1.x, w, acc[4]);  acc[5]  = fmaf(s1.y, w, acc[5]);
    acc[6]  = fmaf(s1.z, w, acc[6]);  acc[7]  = fmaf(s1.w, w, acc[7]);
    acc[8]  = fmaf(s2.x, w, acc[8]);  acc[9]  = fmaf(s2.y, w, acc[9]);
    acc[10] = fmaf(s2.z, w, acc[10]); acc[11] = fmaf(s2.w, w, acc[11]);
    acc[12] = fmaf(s3.x, w, acc[12]); acc[13] = fmaf(s3.y, w, acc[13]);
    acc[14] = fmaf(s3.z, w, acc[14]); acc[15] = fmaf(s3.w, w, acc[15]);
    acc[16] = fmaf(s4.x, w, acc[16]); acc[17] = fmaf(s4.y, w, acc[17]);
    acc[18] = fmaf(s4.z, w, acc[18]); acc[19] = fmaf(s4.w, w, acc[19]);
    acc[20] = fmaf(s5.x, w, acc[20]); acc[21] = fmaf(s5.y, w, acc[21]);
    acc[22] = fmaf(s5.z, w, acc[22]); acc[23] = fmaf(s5.w, w, acc[23]);
    acc[24] = fmaf(s6.x, w, acc[24]); acc[25] = fmaf(s6.y, w, acc[25]);
    acc[26] = fmaf(s6.z, w, acc[26]); acc[27] = fmaf(s6.w, w, acc[27]);
    acc[28] = fmaf(s7.x, w, acc[28]); acc[29] = fmaf(s7.y, w, acc[29]);
  }

  if (ksub == 1) {
#pragma unroll
    for (int m = 0; m < 30; ++m) sred[(t - 128) * 30 + m] = acc[m];
  }
  __syncthreads();
  if (ksub == 0) {
#pragma unroll
    for (int m = 0; m < 30; ++m) {
      const float v = acc[m] + sred[t * 30 + m];
      part[(size_t)(m * 64 + kg) * 1024 + col] = v;
    }
  }
}

// ---------------------------------------------------------------------------
// tail_a: reduce 64 partials + rrelu -> act1[30][1024]. 120 blocks.
// ---------------------------------------------------------------------------
__global__ __launch_bounds__(256) void tail_a_kernel(
    const float* __restrict__ part,
    const float* __restrict__ cb1,
    float* __restrict__ act1)
{
  const int r = blockIdx.x >> 2;
  const int cg = blockIdx.x & 3;
  const int j = cg * 256 + threadIdx.x;
  float s = cb1[j];
  const float* pp = part + (size_t)r * 64 * 1024 + j;
#pragma unroll 8
  for (int q = 0; q < 64; ++q) s += pp[q * 1024];
  act1[r * 1024 + j] = s >= 0.f ? s : RRELU_SLOPE * s;
}

// ---------------------------------------------------------------------------
// tail_b: GEMM2 (1024->256) + relu -> act2. 240 blocks.
// ---------------------------------------------------------------------------
__global__ __launch_bounds__(256) void tail_b_kernel(
    const float* __restrict__ act1,
    const float* __restrict__ w2, const float* __restrict__ cb2,
    float* __restrict__ act2)
{
  __shared__ float sa[1024];
  __shared__ float sp[256];
  const int r = blockIdx.x >> 3;
  const int cg = blockIdx.x & 7;
  const int t = threadIdx.x;
  const int c = t & 31;
  const int ks = t >> 5;
  const int col = cg * 32 + c;

  for (int i = t; i < 1024; i += 256) sa[i] = act1[r * 1024 + i];
  __syncthreads();

  float acc = 0.f;
  const int k0 = ks * 128;
  for (int kk = k0; kk < k0 + 128; kk += 4) {
    const float4 a = *reinterpret_cast<const float4*>(&sa[kk]);
    acc = fmaf(a.x, w2[(kk + 0) * 256 + col], acc);
    acc = fmaf(a.y, w2[(kk + 1) * 256 + col], acc);
    acc = fmaf(a.z, w2[(kk + 2) * 256 + col], acc);
    acc = fmaf(a.w, w2[(kk + 3) * 256 + col], acc);
  }
  sp[t] = acc;
  __syncthreads();
  if (t < 32) {
    float s = cb2[col];
#pragma unroll
    for (int q = 0; q < 8; ++q) s += sp[q * 32 + t];
    act2[r * 256 + cg * 32 + t] = fmaxf(s, 0.f);
  }
}

// ---------------------------------------------------------------------------
// tail_c: GEMM3 (256->64, 4-way k-split) + GEMM4 (64->3) + log_softmax.
// ---------------------------------------------------------------------------
__global__ __launch_bounds__(256) void tail_c_kernel(
    const float* __restrict__ act2,
    const float* __restrict__ w3, const float* __restrict__ cb3,
    const float* __restrict__ w4, const float* __restrict__ cb4,
    float* __restrict__ out)
{
  __shared__ float sa[256];
  __shared__ float sp[256];
  __shared__ float sc3[64];
  __shared__ float slg[3];
  const int r = blockIdx.x, t = threadIdx.x;
  const int c = t & 63;
  const int ks = t >> 6;

  sa[t] = act2[r * 256 + t];
  __syncthreads();
  {
    float acc = 0.f;
    const int k0 = ks * 64;
#pragma unroll 4
    for (int kk = k0; kk < k0 + 64; ++kk)
      acc = fmaf(sa[kk], w3[kk * 64 + c], acc);
    sp[t] = acc;
  }
  __syncthreads();
  if (t < 64) {
    const float s = cb3[t] + sp[t] + sp[t + 64] + sp[t + 128] + sp[t + 192];
    sc3[t] = fmaxf(s, 0.f);
  }
  __syncthreads();
  if (t < 3) {
    float acc = cb4[t];
#pragma unroll
    for (int kk = 0; kk < 64; ++kk) acc = fmaf(sc3[kk], w4[kk * 3 + t], acc);
    slg[t] = acc;
  }
  __syncthreads();
  if (t == 0) {
    float m = fmaxf(slg[0], fmaxf(slg[1], slg[2]));
    float se = __expf(slg[0] - m) + __expf(slg[1] - m) + __expf(slg[2] - m);
    float lse = m + logf(se);
    out[r * 3 + 0] = slg[0] - lse;
    out[r * 3 + 1] = slg[1] - lse;
    out[r * 3 + 2] = slg[2] - lse;
  }
}

extern "C" void kernel_launch(void* const* d_in, const int* in_sizes, int n_in,
                              void* d_out, int out_size, void* d_ws, size_t ws_size,
                              hipStream_t stream) {
  const float* x    = (const float*)d_in[0];
  const float* w1c  = (const float*)d_in[1];
  const float* b1c  = (const float*)d_in[2];
  const float* g1   = (const float*)d_in[3];
  const float* bb1  = (const float*)d_in[4];
  const float* w2c  = (const float*)d_in[5];
  const float* b2c  = (const float*)d_in[6];
  const float* g2   = (const float*)d_in[7];
  const float* bb2  = (const float*)d_in[8];
  const float* w3c  = (const float*)d_in[9];
  const float* b3c  = (const float*)d_in[10];
  const float* g3   = (const float*)d_in[11];
  const float* bb3  = (const float*)d_in[12];
  const float* fcw  = (const float*)d_in[13];
  const float* fcb  = (const float*)d_in[14];
  const float* sw1  = (const float*)d_in[15];
  const float* sb1  = (const float*)d_in[16];
  const float* sw2  = (const float*)d_in[17];
  const float* sb2  = (const float*)d_in[18];
  const float* sw3  = (const float*)d_in[19];
  const float* sb3  = (const float*)d_in[20];
  const float* sw4  = (const float*)d_in[21];
  const float* sb4  = (const float*)d_in[22];
  const float* cw1  = (const float*)d_in[23];
  const float* cb1  = (const float*)d_in[24];
  const float* cw2  = (const float*)d_in[25];
  const float* cb2  = (const float*)d_in[26];
  const float* cw3  = (const float*)d_in[27];
  const float* cb3  = (const float*)d_in[28];
  const float* cw4  = (const float*)d_in[29];
  const float* cb4  = (const float*)d_in[30];

  float* ws = (float*)d_ws;
  float* Ga    = ws;                     // 129600
  float* Gb    = ws + 129600;            // -> 259200
  float* part  = ws + 259200;            // 30*64*1024 -> 2225280
  float* bgagb = ws + 2225280;           // 64 -> 2225344
  float* act1  = ws + 2225344;           // 30720 -> 2256064
  float* act2  = ws + 2256064;           // 7680 -> 2263744
  float* subjectsT = ws + 2263744;       // 9045*32 = 289440 -> 2553184
  unsigned short* wsu = (unsigned short*)(ws + 2553184);
  unsigned short* w2frag    = wsu;             // 4096 sh
  unsigned short* w3frag    = wsu + 4096;      // -> 13312
  unsigned short* bfragGG   = wsu + 13312;     // -> 152576
  unsigned short* act3      = wsu + 152576;    // -> 8965376 (4050*2176)

  setup_kernel<<<75, 256, 0, stream>>>(w2c, g2, w3c, g3, fcw, fcb, sw1, sb1,
                                       w2frag, w3frag, bfragGG, bgagb);
  fe_kernel<<<2025, 128, 0, stream>>>(x, w1c, b1c, g1, bb1, b2c, g2, bb2,
                                      b3c, g3, bb3, w2frag, w3frag, act3);
  gagb_kernel<<<254, 256, 0, stream>>>(act3, bfragGG, bgagb, Ga, Gb);
  sim_kernel<<<960, 256, 0, stream>>>(Ga, Gb, sw2, sb2, sw3, sb3, sw4, sb4, subjectsT);
  c1_kernel<<<512, 256, 0, stream>>>(subjectsT, cw1, part);
  tail_a_kernel<<<120, 256, 0, stream>>>(part, cb1, act1);
  tail_b_kernel<<<240, 256, 0, stream>>>(act1, cw2, cb2, act2);
  tail_c_kernel<<<30, 256, 0, stream>>>(act2, cw3, cb3, cw4, cb4, (float*)d_out);
}

// Round 4
// 290.133 us; speedup vs baseline: 1.0183x; 1.0183x over previous
//
#include <hip/hip_runtime.h>
#include <math.h>

#define BN_SCALE 0.99999500003749967f
#define RRELU_SLOPE 0.22916666666666666f

static __device__ __forceinline__ float leaky(float v) { return v > 0.f ? v : 0.01f * v; }

typedef __attribute__((ext_vector_type(8))) short bf16x8;
typedef __attribute__((ext_vector_type(4))) float f32x4;

static __device__ __forceinline__ unsigned short f2bf(float f) {
  unsigned u = __builtin_bit_cast(unsigned, f);
  u = (u + 0x7FFFu + ((u >> 16) & 1u)) >> 16;
  return (unsigned short)u;
}

// ---------------------------------------------------------------------------
// setup: conv frags, Wgagb B-frags, folded biases. 75 blocks x 256.
// (w1 transpose ELIMINATED: c1 reads cw1 directly in fp32.)
// ---------------------------------------------------------------------------
__global__ __launch_bounds__(256) void setup_kernel(
    const float* __restrict__ w2c, const float* __restrict__ g2,
    const float* __restrict__ w3c, const float* __restrict__ g3,
    const float* __restrict__ fcw, const float* __restrict__ fcb,
    const float* __restrict__ w1,  const float* __restrict__ b1,
    unsigned short* __restrict__ w2frag,
    unsigned short* __restrict__ w3frag,
    unsigned short* __restrict__ bfragGG,
    float* __restrict__ bgagb)
{
  const int item = blockIdx.x * 256 + threadIdx.x;
  if (item < 512) {                      // conv2 A-frags
    const int tl = item >> 6, lane = item & 63;
    const int mt = tl >> 1, kc = tl & 1;
    const int lr = lane & 15, quad = lane >> 4;
    const int c = mt * 16 + lr;
    const float gs = g2[c] * BN_SCALE;
#pragma unroll
    for (int j = 0; j < 8; ++j) {
      const int k = quad * 8 + j;
      float v;
      if (kc == 0) { const int tap = k >> 4, ci = k & 15; v = w2c[c * 48 + ci * 3 + tap] * gs; }
      else         { v = (k < 16) ? w2c[c * 48 + k * 3 + 2] * gs : 0.f; }
      w2frag[item * 8 + j] = f2bf(v);
    }
  } else if (item < 1664) {              // conv3 A-frags
    const int it = item - 512;
    const int tl = it >> 6, lane = it & 63;
    const int mt = tl / 3, tap = tl - mt * 3;
    const int lr = lane & 15, quad = lane >> 4;
    const int c = mt * 16 + lr;
    const float gs = g3[c] * BN_SCALE;
#pragma unroll
    for (int j = 0; j < 8; ++j) {
      const int ci = quad * 8 + j;
      w3frag[it * 8 + j] = f2bf(w3c[c * 96 + ci * 3 + tap] * gs);
    }
  } else if (item < 19072) {             // Wgagb B-frags
    const int it = item - 1664;
    const int chunk = it >> 8;
    const int rem = it & 255;
    const int nt = rem >> 6;
    const int lane = rem & 63;
    const int lr = lane & 15, quad = lane >> 4;
    const int n = nt * 16 + lr;
    const int off = (n >= 32) ? 32 : 0;
    const int nj = n & 31;
    float w1col[32];
#pragma unroll 8
    for (int q = 0; q < 32; ++q) w1col[q] = w1[(q + off) * 32 + nj];
#pragma unroll
    for (int j = 0; j < 8; ++j) {
      const int k = chunk * 32 + quad * 8 + j;
      float v = 0.f;
      if (k < 2160) {
        const float* fr = fcw + (size_t)k * 32;
#pragma unroll 8
        for (int q = 0; q < 32; ++q) v = fmaf(fr[q], w1col[q], v);
      }
      bfragGG[(size_t)it * 8 + j] = f2bf(v);
    }
  } else if (item < 19136) {             // folded biases
    const int n = item - 19072;
    const int off = (n >= 32) ? 32 : 0;
    const int nj = n & 31;
    float s = (n < 32) ? b1[nj] : 0.f;
    for (int q = 0; q < 32; ++q) s = fmaf(fcb[q], w1[(q + off) * 32 + nj], s);
    bgagb[n] = s;
  }
}

// ---------------------------------------------------------------------------
// fe: wave-autonomous (R0 structure). s2t OVERLAYS s1t (safe: tile nt reads
// rows 16nt..16nt+17 before writing rows <=16nt+15; later tiles read only
// higher rows; DS pipe in-order per wave). leaky applied AFTER pool-max
// (bit-exact, monotone). Arena 6912 B per wave -> 11 blocks (22 waves)/CU.
// ---------------------------------------------------------------------------
__global__ __launch_bounds__(128) void fe_kernel(
    const float* __restrict__ x,
    const float* __restrict__ w1c, const float* __restrict__ b1c,
    const float* __restrict__ g1,  const float* __restrict__ bb1,
    const float* __restrict__ b2c, const float* __restrict__ g2, const float* __restrict__ bb2,
    const float* __restrict__ b3c, const float* __restrict__ g3, const float* __restrict__ bb3,
    const unsigned short* __restrict__ w2frag,
    const unsigned short* __restrict__ w3frag,
    unsigned short* __restrict__ act3)
{
  __shared__ __align__(16) char smem[2 * 6912];
  const int t = threadIdx.x;
  const int wv = t >> 6, lane = t & 63, quad = lane >> 4, lr = lane & 15;
  const int n = blockIdx.x * 2 + wv;

  char* A = smem + wv * 6912;
  unsigned short* buf = (unsigned short*)A;   // s1t: 194r x 16sh / s2t: 98r x 32sh (overlaid)
  float* be2 = (float*)(A + 6272);            // 64
  float* be3 = (float*)(A + 6528);            // 96

  bf16x8 a2[4][2];
#pragma unroll
  for (int mt = 0; mt < 4; ++mt)
#pragma unroll
    for (int kc = 0; kc < 2; ++kc)
      a2[mt][kc] = *(const bf16x8*)(w2frag + ((mt * 2 + kc) * 64 + lane) * 8);

  be2[lane] = b2c[lane] * (g2[lane] * BN_SCALE) + bb2[lane];
  be3[lane] = b3c[lane] * (g3[lane] * BN_SCALE) + bb3[lane];
  if (lane < 32) be3[64 + lane] = b3c[64 + lane] * (g3[64 + lane] * BN_SCALE) + bb3[64 + lane];
  ((unsigned*)buf)[1488 + lane] = 0;          // s1t pad rows 186..193

  const int cp = lane & 7;
  float u[4][3], bbr[4];
#pragma unroll
  for (int d = 0; d < 4; ++d) {
    const int c = cp * 4 + d;
    const float gs = g1[c] * BN_SCALE;
    u[d][0] = w1c[c * 3 + 0] * gs;
    u[d][1] = w1c[c * 3 + 1] * gs;
    u[d][2] = w1c[c * 3 + 2] * gs;
    bbr[d] = b1c[c] * gs + bb1[c];
  }

  // ---- stage 1: conv1+bn+pool+leaky -> buf rows 0..185 (16sh stride) ----
  const float* xr = x + (size_t)n * 375;
  for (int o = lane; o < 1488; o += 64) {
    const int l = o >> 3;
    const int p = 2 * l;
    const float x0 = xr[p], x1 = xr[p + 1], x2 = xr[p + 2], x3 = xr[p + 3];
    unsigned pk = 0;
#pragma unroll
    for (int uu = 0; uu < 2; ++uu) {
      float m = -3.4e38f;
#pragma unroll
      for (int dc = 0; dc < 2; ++dc) {
        const int d = uu * 2 + dc;
        const float v0 = fmaf(x0, u[d][0], fmaf(x1, u[d][1], fmaf(x2, u[d][2], bbr[d])));
        const float v1 = fmaf(x1, u[d][0], fmaf(x2, u[d][1], fmaf(x3, u[d][2], bbr[d])));
        m = fmaxf(m, fmaxf(v0, v1));
      }
      pk |= (unsigned)f2bf(leaky(m)) << (16 * uu);
    }
    ((unsigned*)buf)[l * 8 + cp] = pk;
  }

  float be2r[4][4];
#pragma unroll
  for (int mt = 0; mt < 4; ++mt)
#pragma unroll
    for (int r = 0; r < 4; ++r) be2r[mt][r] = be2[mt * 16 + quad * 4 + r];

  // ---- conv2: 12 n-tiles; reads s1t rows, writes s2t rows (overlaid) ----
#pragma unroll 2
  for (int nt = 0; nt < 12; ++nt) {
    const int nrow = nt * 16 + lr;
    bf16x8 b0 = *(const bf16x8*)(buf + (nrow + (quad >> 1)) * 16 + (quad & 1) * 8);
    bf16x8 b1 = *(const bf16x8*)(buf + (nrow + 2) * 16 + (quad & 1) * 8);
    f32x4 acc[4];
#pragma unroll
    for (int mt = 0; mt < 4; ++mt)
#pragma unroll
      for (int r = 0; r < 4; ++r) acc[mt][r] = be2r[mt][r];
#pragma unroll
    for (int mt = 0; mt < 4; ++mt)
      acc[mt] = __builtin_amdgcn_mfma_f32_16x16x32_bf16(a2[mt][0], b0, acc[mt], 0, 0, 0);
#pragma unroll
    for (int mt = 0; mt < 4; ++mt)
      acc[mt] = __builtin_amdgcn_mfma_f32_16x16x32_bf16(a2[mt][1], b1, acc[mt], 0, 0, 0);
#pragma unroll
    for (int mt = 0; mt < 4; ++mt) {
      float o[4];
#pragma unroll
      for (int r = 0; r < 4; ++r)
        o[r] = fmaxf(acc[mt][r], __shfl_xor(acc[mt][r], 1));
      if ((lr & 1) == 0) {
        const int np = nrow >> 1;
        if (np <= 91) {
          const float m0 = leaky(fmaxf(o[0], o[1]));
          const float m1 = leaky(fmaxf(o[2], o[3]));
          const unsigned pk = (unsigned)f2bf(m0) | ((unsigned)f2bf(m1) << 16);
          ((unsigned*)buf)[np * 16 + mt * 4 + quad] = pk;
        }
      }
    }
  }

  // ---- zero s2t pad rows 92..97 (safe: conv2 done with s1t tail) ----
  ((unsigned*)buf)[1472 + lane] = 0;
  if (lane < 32) ((unsigned*)buf)[1536 + lane] = 0;

  // ---- conv3: 6x6 tiles x 3 tap-MFMAs; epilogue -> act3 (global) ----
  unsigned short* actr = act3 + (size_t)n * 2176;
  for (int mt = 0; mt < 6; ++mt) {
    bf16x8 a3[3];
#pragma unroll
    for (int tap = 0; tap < 3; ++tap)
      a3[tap] = *(const bf16x8*)(w3frag + ((mt * 3 + tap) * 64 + lane) * 8);
    float be3r[4];
#pragma unroll
    for (int r = 0; r < 4; ++r) be3r[r] = be3[mt * 16 + quad * 4 + r];
#pragma unroll
    for (int nt = 0; nt < 6; ++nt) {
      const int nrow = nt * 16 + lr;
      f32x4 acc;
#pragma unroll
      for (int r = 0; r < 4; ++r) acc[r] = be3r[r];
#pragma unroll
      for (int tap = 0; tap < 3; ++tap) {
        bf16x8 b = *(const bf16x8*)(buf + (nrow + tap) * 32 + quad * 8);
        acc = __builtin_amdgcn_mfma_f32_16x16x32_bf16(a3[tap], b, acc, 0, 0, 0);
      }
      float o[4];
#pragma unroll
      for (int r = 0; r < 4; ++r)
        o[r] = fmaxf(acc[r], __shfl_xor(acc[r], 1));
      if ((lr & 1) == 0) {
        const int np = nrow >> 1;
        if (np <= 44) {
          const int mp = mt * 8 + quad * 2;
          actr[mp * 45 + np] = f2bf(leaky(fmaxf(o[0], o[1])));
          actr[(mp + 1) * 45 + np] = f2bf(leaky(fmaxf(o[2], o[3])));
        }
      }
    }
  }
  if (lane < 16) actr[2160 + lane] = 0;
}

// ---------------------------------------------------------------------------
// gagb: 254 blocks x 16 rows; 4 waves split K (17 chunks each); LDS reduce.
// ---------------------------------------------------------------------------
__global__ __launch_bounds__(256) void gagb_kernel(
    const unsigned short* __restrict__ act3,
    const unsigned short* __restrict__ bfragGG,
    const float* __restrict__ bgagb,
    float* __restrict__ Ga, float* __restrict__ Gb)
{
  __shared__ f32x4 sred[3][4][64];
  const int t = threadIdx.x;
  const int wv = t >> 6, lane = t & 63, quad = lane >> 4, lr = lane & 15;
  const int m0 = blockIdx.x * 16;
  const int arow = min(m0 + lr, 4049);

  f32x4 acc[4] = {};
  const int c0 = wv * 17;
  for (int chunk = c0; chunk < c0 + 17; ++chunk) {
    const bf16x8 a = *(const bf16x8*)(act3 + (size_t)arow * 2176 + chunk * 32 + quad * 8);
#pragma unroll
    for (int nt = 0; nt < 4; ++nt) {
      const bf16x8 b = *(const bf16x8*)(bfragGG + ((size_t)(chunk * 4 + nt) * 64 + lane) * 8);
      acc[nt] = __builtin_amdgcn_mfma_f32_16x16x32_bf16(a, b, acc[nt], 0, 0, 0);
    }
  }
  if (wv > 0) {
#pragma unroll
    for (int nt = 0; nt < 4; ++nt) sred[wv - 1][nt][lane] = acc[nt];
  }
  __syncthreads();
  if (wv == 0) {
#pragma unroll
    for (int nt = 0; nt < 4; ++nt) {
      f32x4 s = acc[nt];
#pragma unroll
      for (int q = 0; q < 3; ++q) {
        const f32x4 o = sred[q][nt][lane];
#pragma unroll
        for (int r = 0; r < 4; ++r) s[r] += o[r];
      }
      const int col = nt * 16 + lr;
      const float bias = bgagb[col];
#pragma unroll
      for (int r = 0; r < 4; ++r) {
        const int row = m0 + quad * 4 + r;
        if (row < 4050) {
          const float v = s[r] + bias;
          if (col < 32) Ga[row * 32 + col] = v;
          else          Gb[row * 32 + (col - 32)] = v;
        }
      }
    }
  }
}

// ---------------------------------------------------------------------------
// sim: 960 blocks = 30 subjects x 32 chunks; writes f32 subjectsT[p][b]
// (k-major rows of 32 floats so c1 can broadcast-read 30 subjects per k).
// ---------------------------------------------------------------------------
__global__ __launch_bounds__(256) void sim_kernel(
    const float* __restrict__ Ga, const float* __restrict__ Gb,
    const float* __restrict__ w2, const float* __restrict__ b2,
    const float* __restrict__ w3, const float* __restrict__ b3,
    const float* __restrict__ w4, const float* __restrict__ b4,
    float* __restrict__ subjectsT)
{
  __shared__ float sGa[135 * 36];
  __shared__ float sGb[135 * 36];
  __shared__ float sw2[512], sw3[128], sw4[8];
  __shared__ float sb2[16], sb3[8], sb4v[1];

  const int t = threadIdx.x;
  const int b = blockIdx.x >> 5;
  const int c = blockIdx.x & 31;

  for (int i = t; i < 4320; i += 256) {
    const int r = i >> 5, col = i & 31;
    sGa[r * 36 + col] = Ga[b * 4320 + i];
    sGb[r * 36 + col] = Gb[b * 4320 + i];
  }
  for (int i = t; i < 512; i += 256) sw2[i] = w2[i];
  if (t < 128) sw3[t] = w3[t];
  if (t < 8) sw4[t] = w4[t];
  if (t < 16) sb2[t] = b2[t];
  if (t < 8) sb3[t] = b3[t];
  if (t == 0) sb4v[0] = b4[0];
  __syncthreads();

  const int pend = min(9045, (c + 1) * 283);
  for (int p = c * 283 + t; p < pend; p += 256) {
    int i = (int)((269.0f - sqrtf((float)(72361 - 8 * p))) * 0.5f);
    i = max(0, min(133, i));
    while (134 * (i + 1) - ((i + 1) * i) / 2 <= p) ++i;
    while (134 * i - (i * (i - 1)) / 2 > p) --i;
    const int j = i + 1 + (p - (134 * i - (i * (i - 1)) / 2));

    float h1[32];
#pragma unroll
    for (int q = 0; q < 8; ++q) {
      const float4 va = *(const float4*)(&sGa[i * 36 + 4 * q]);
      const float4 vb = *(const float4*)(&sGb[j * 36 + 4 * q]);
      h1[4 * q + 0] = fmaxf(va.x + vb.x, 0.f);
      h1[4 * q + 1] = fmaxf(va.y + vb.y, 0.f);
      h1[4 * q + 2] = fmaxf(va.z + vb.z, 0.f);
      h1[4 * q + 3] = fmaxf(va.w + vb.w, 0.f);
    }

    float h2[16];
#pragma unroll
    for (int jj = 0; jj < 16; ++jj) h2[jj] = sb2[jj];
#pragma unroll 8
    for (int ii = 0; ii < 32; ++ii) {
      const float av = h1[ii];
      const float4* wr = reinterpret_cast<const float4*>(&sw2[ii * 16]);
#pragma unroll
      for (int r = 0; r < 4; ++r) {
        float4 w = wr[r];
        h2[4 * r + 0] = fmaf(av, w.x, h2[4 * r + 0]);
        h2[4 * r + 1] = fmaf(av, w.y, h2[4 * r + 1]);
        h2[4 * r + 2] = fmaf(av, w.z, h2[4 * r + 2]);
        h2[4 * r + 3] = fmaf(av, w.w, h2[4 * r + 3]);
      }
    }
#pragma unroll
    for (int jj = 0; jj < 16; ++jj) h2[jj] = fmaxf(h2[jj], 0.f);

    float h3[8];
#pragma unroll
    for (int jj = 0; jj < 8; ++jj) h3[jj] = sb3[jj];
#pragma unroll
    for (int ii = 0; ii < 16; ++ii) {
      const float av = h2[ii];
      const float4* wr = reinterpret_cast<const float4*>(&sw3[ii * 8]);
#pragma unroll
      for (int r = 0; r < 2; ++r) {
        float4 w = wr[r];
        h3[4 * r + 0] = fmaf(av, w.x, h3[4 * r + 0]);
        h3[4 * r + 1] = fmaf(av, w.y, h3[4 * r + 1]);
        h3[4 * r + 2] = fmaf(av, w.z, h3[4 * r + 2]);
        h3[4 * r + 3] = fmaf(av, w.w, h3[4 * r + 3]);
      }
    }
#pragma unroll
    for (int jj = 0; jj < 8; ++jj) h3[jj] = fmaxf(h3[jj], 0.f);

    float z = sb4v[0];
#pragma unroll
    for (int ii = 0; ii < 8; ++ii) z = fmaf(h3[ii], sw4[ii], z);

    const float az = fabsf(z);
    const float e = __expf(-2.f * az);
    const float rr = (1.f - e) / (1.f + e);
    const float val = copysignf(rr, z);

    subjectsT[(size_t)p * 32 + b] = val;
  }
}

// ---------------------------------------------------------------------------
// c1 v3: C(30x1024) = subjectsT^T @ cw1, fp32, register-tiled so it CANNOT
// spill (R3's acc[30] version was demoted to 32 VGPRs -> scratch-serialized,
// 62us). 512 blocks = 64 kg x 8 cg(128 cols); 256 thr = 32 colquads x 8
// mgroups(4 subjects; mg7 has 2). Per thread: float4 acc[4] (16 VGPR),
// per-k: 1 coalesced float4 cw1 load (streaming) + 1 wave-uniform float4
// subjectsT load (L1/L2-resident) + 16 FMAs. No LDS, no barrier.
// Writes same part layout -> tail_a unchanged.
// ---------------------------------------------------------------------------
__global__ __launch_bounds__(256) void c1_kernel(
    const float* __restrict__ subjectsT,
    const float* __restrict__ cw1,
    float* __restrict__ part)
{
  const int t = threadIdx.x;
  const int cg = blockIdx.x & 7;
  const int kg = blockIdx.x >> 3;
  const int cq = t & 31;                // 32 col-quads -> 128 cols
  const int mg = t >> 5;                // 0..7 (wave pairs share mg? mg uniform per half-wave; fine)
  const int col = cg * 128 + cq * 4;
  const int mbase = mg * 4;             // mg7: subjects 28,29 valid
  const int nm = (mg == 7) ? 2 : 4;

  const int k0 = kg * 142;
  const int kn = min(9045 - k0, 142);

  f32x4 acc0 = {0.f, 0.f, 0.f, 0.f};
  f32x4 acc1 = {0.f, 0.f, 0.f, 0.f};
  f32x4 acc2 = {0.f, 0.f, 0.f, 0.f};
  f32x4 acc3 = {0.f, 0.f, 0.f, 0.f};

  const float* wp = cw1 + (size_t)k0 * 1024 + col;
  const float* sp = subjectsT + (size_t)k0 * 32 + mbase;

  for (int kk = 0; kk < kn; ++kk) {
    const float4 w = *(const float4*)(wp + (size_t)kk * 1024);
    const float4 s = *(const float4*)(sp + (size_t)kk * 32);
    acc0[0] = fmaf(s.x, w.x, acc0[0]); acc0[1] = fmaf(s.x, w.y, acc0[1]);
    acc0[2] = fmaf(s.x, w.z, acc0[2]); acc0[3] = fmaf(s.x, w.w, acc0[3]);
    acc1[0] = fmaf(s.y, w.x, acc1[0]); acc1[1] = fmaf(s.y, w.y, acc1[1]);
    acc1[2] = fmaf(s.y, w.z, acc1[2]); acc1[3] = fmaf(s.y, w.w, acc1[3]);
    acc2[0] = fmaf(s.z, w.x, acc2[0]); acc2[1] = fmaf(s.z, w.y, acc2[1]);
    acc2[2] = fmaf(s.z, w.z, acc2[2]); acc2[3] = fmaf(s.z, w.w, acc2[3]);
    acc3[0] = fmaf(s.w, w.x, acc3[0]); acc3[1] = fmaf(s.w, w.y, acc3[1]);
    acc3[2] = fmaf(s.w, w.z, acc3[2]); acc3[3] = fmaf(s.w, w.w, acc3[3]);
  }

  // store nm rows (mg7 stores 2: subjects 28,29; acc2/acc3 hold garbage pad)
  *(f32x4*)(&part[(size_t)((mbase + 0) * 64 + kg) * 1024 + col]) = acc0;
  if (nm > 1) *(f32x4*)(&part[(size_t)((mbase + 1) * 64 + kg) * 1024 + col]) = acc1;
  if (nm > 2) *(f32x4*)(&part[(size_t)((mbase + 2) * 64 + kg) * 1024 + col]) = acc2;
  if (nm > 3) *(f32x4*)(&part[(size_t)((mbase + 3) * 64 + kg) * 1024 + col]) = acc3;
}

// ---------------------------------------------------------------------------
// tail_a: reduce 64 partials + rrelu -> act1[30][1024]. 120 blocks.
// ---------------------------------------------------------------------------
__global__ __launch_bounds__(256) void tail_a_kernel(
    const float* __restrict__ part,
    const float* __restrict__ cb1,
    float* __restrict__ act1)
{
  const int r = blockIdx.x >> 2;
  const int cg = blockIdx.x & 3;
  const int j = cg * 256 + threadIdx.x;
  float s = cb1[j];
  const float* pp = part + (size_t)r * 64 * 1024 + j;
#pragma unroll 8
  for (int q = 0; q < 64; ++q) s += pp[q * 1024];
  act1[r * 1024 + j] = s >= 0.f ? s : RRELU_SLOPE * s;
}

// ---------------------------------------------------------------------------
// tail_b: GEMM2 (1024->256) + relu -> act2. 240 blocks.
// ---------------------------------------------------------------------------
__global__ __launch_bounds__(256) void tail_b_kernel(
    const float* __restrict__ act1,
    const float* __restrict__ w2, const float* __restrict__ cb2,
    float* __restrict__ act2)
{
  __shared__ float sa[1024];
  __shared__ float sp[256];
  const int r = blockIdx.x >> 3;
  const int cg = blockIdx.x & 7;
  const int t = threadIdx.x;
  const int c = t & 31;
  const int ks = t >> 5;
  const int col = cg * 32 + c;

  for (int i = t; i < 1024; i += 256) sa[i] = act1[r * 1024 + i];
  __syncthreads();

  float acc = 0.f;
  const int k0 = ks * 128;
  for (int kk = k0; kk < k0 + 128; kk += 4) {
    const float4 a = *reinterpret_cast<const float4*>(&sa[kk]);
    acc = fmaf(a.x, w2[(kk + 0) * 256 + col], acc);
    acc = fmaf(a.y, w2[(kk + 1) * 256 + col], acc);
    acc = fmaf(a.z, w2[(kk + 2) * 256 + col], acc);
    acc = fmaf(a.w, w2[(kk + 3) * 256 + col], acc);
  }
  sp[t] = acc;
  __syncthreads();
  if (t < 32) {
    float s = cb2[col];
#pragma unroll
    for (int q = 0; q < 8; ++q) s += sp[q * 32 + t];
    act2[r * 256 + cg * 32 + t] = fmaxf(s, 0.f);
  }
}

// ---------------------------------------------------------------------------
// tail_c: GEMM3 (256->64, 4-way k-split) + GEMM4 (64->3) + log_softmax.
// ---------------------------------------------------------------------------
__global__ __launch_bounds__(256) void tail_c_kernel(
    const float* __restrict__ act2,
    const float* __restrict__ w3, const float* __restrict__ cb3,
    const float* __restrict__ w4, const float* __restrict__ cb4,
    float* __restrict__ out)
{
  __shared__ float sa[256];
  __shared__ float sp[256];
  __shared__ float sc3[64];
  __shared__ float slg[3];
  const int r = blockIdx.x, t = threadIdx.x;
  const int c = t & 63;
  const int ks = t >> 6;

  sa[t] = act2[r * 256 + t];
  __syncthreads();
  {
    float acc = 0.f;
    const int k0 = ks * 64;
#pragma unroll 4
    for (int kk = k0; kk < k0 + 64; ++kk)
      acc = fmaf(sa[kk], w3[kk * 64 + c], acc);
    sp[t] = acc;
  }
  __syncthreads();
  if (t < 64) {
    const float s = cb3[t] + sp[t] + sp[t + 64] + sp[t + 128] + sp[t + 192];
    sc3[t] = fmaxf(s, 0.f);
  }
  __syncthreads();
  if (t < 3) {
    float acc = cb4[t];
#pragma unroll
    for (int kk = 0; kk < 64; ++kk) acc = fmaf(sc3[kk], w4[kk * 3 + t], acc);
    slg[t] = acc;
  }
  __syncthreads();
  if (t == 0) {
    float m = fmaxf(slg[0], fmaxf(slg[1], slg[2]));
    float se = __expf(slg[0] - m) + __expf(slg[1] - m) + __expf(slg[2] - m);
    float lse = m + logf(se);
    out[r * 3 + 0] = slg[0] - lse;
    out[r * 3 + 1] = slg[1] - lse;
    out[r * 3 + 2] = slg[2] - lse;
  }
}

extern "C" void kernel_launch(void* const* d_in, const int* in_sizes, int n_in,
                              void* d_out, int out_size, void* d_ws, size_t ws_size,
                              hipStream_t stream) {
  const float* x    = (const float*)d_in[0];
  const float* w1c  = (const float*)d_in[1];
  const float* b1c  = (const float*)d_in[2];
  const float* g1   = (const float*)d_in[3];
  const float* bb1  = (const float*)d_in[4];
  const float* w2c  = (const float*)d_in[5];
  const float* b2c  = (const float*)d_in[6];
  const float* g2   = (const float*)d_in[7];
  const float* bb2  = (const float*)d_in[8];
  const float* w3c  = (const float*)d_in[9];
  const float* b3c  = (const float*)d_in[10];
  const float* g3   = (const float*)d_in[11];
  const float* bb3  = (const float*)d_in[12];
  const float* fcw  = (const float*)d_in[13];
  const float* fcb  = (const float*)d_in[14];
  const float* sw1  = (const float*)d_in[15];
  const float* sb1  = (const float*)d_in[16];
  const float* sw2  = (const float*)d_in[17];
  const float* sb2  = (const float*)d_in[18];
  const float* sw3  = (const float*)d_in[19];
  const float* sb3  = (const float*)d_in[20];
  const float* sw4  = (const float*)d_in[21];
  const float* sb4  = (const float*)d_in[22];
  const float* cw1  = (const float*)d_in[23];
  const float* cb1  = (const float*)d_in[24];
  const float* cw2  = (const float*)d_in[25];
  const float* cb2  = (const float*)d_in[26];
  const float* cw3  = (const float*)d_in[27];
  const float* cb3  = (const float*)d_in[28];
  const float* cw4  = (const float*)d_in[29];
  const float* cb4  = (const float*)d_in[30];

  float* ws = (float*)d_ws;
  float* Ga    = ws;                     // 129600
  float* Gb    = ws + 129600;            // -> 259200
  float* part  = ws + 259200;            // 30*64*1024 -> 2225280
  float* bgagb = ws + 2225280;           // 64 -> 2225344
  float* act1  = ws + 2225344;           // 30720 -> 2256064
  float* act2  = ws + 2256064;           // 7680 -> 2263744
  float* subjectsT = ws + 2263744;       // 9045*32 = 289440 -> 2553184
  unsigned short* wsu = (unsigned short*)(ws + 2553184);
  unsigned short* w2frag    = wsu;             // 4096 sh
  unsigned short* w3frag    = wsu + 4096;      // -> 13312
  unsigned short* bfragGG   = wsu + 13312;     // -> 152576
  unsigned short* act3      = wsu + 152576;    // -> 8965376 (4050*2176)

  setup_kernel<<<75, 256, 0, stream>>>(w2c, g2, w3c, g3, fcw, fcb, sw1, sb1,
                                       w2frag, w3frag, bfragGG, bgagb);
  fe_kernel<<<2025, 128, 0, stream>>>(x, w1c, b1c, g1, bb1, b2c, g2, bb2,
                                      b3c, g3, bb3, w2frag, w3frag, act3);
  gagb_kernel<<<254, 256, 0, stream>>>(act3, bfragGG, bgagb, Ga, Gb);
  sim_kernel<<<960, 256, 0, stream>>>(Ga, Gb, sw2, sb2, sw3, sb3, sw4, sb4, subjectsT);
  c1_kernel<<<512, 256, 0, stream>>>(subjectsT, cw1, part);
  tail_a_kernel<<<120, 256, 0, stream>>>(part, cb1, act1);
  tail_b_kernel<<<240, 256, 0, stream>>>(act1, cw2, cb2, act2);
  tail_c_kernel<<<30, 256, 0, stream>>>(act2, cw3, cb3, cw4, cb4, (float*)d_out);
}

// Round 5
// 277.843 us; speedup vs baseline: 1.0633x; 1.0442x over previous
//
#include <hip/hip_runtime.h>
#include <math.h>

#define BN_SCALE 0.99999500003749967f
#define RRELU_SLOPE 0.22916666666666666f

static __device__ __forceinline__ float leaky(float v) { return v > 0.f ? v : 0.01f * v; }

typedef __attribute__((ext_vector_type(8))) short bf16x8;
typedef __attribute__((ext_vector_type(4))) float f32x4;

static __device__ __forceinline__ unsigned short f2bf(float f) {
  unsigned u = __builtin_bit_cast(unsigned, f);
  u = (u + 0x7FFFu + ((u >> 16) & 1u)) >> 16;
  return (unsigned short)u;
}

// ---------------------------------------------------------------------------
// setup: conv frags, Wgagb B-frags, folded biases. 75 blocks x 256.
// ---------------------------------------------------------------------------
__global__ __launch_bounds__(256) void setup_kernel(
    const float* __restrict__ w2c, const float* __restrict__ g2,
    const float* __restrict__ w3c, const float* __restrict__ g3,
    const float* __restrict__ fcw, const float* __restrict__ fcb,
    const float* __restrict__ w1,  const float* __restrict__ b1,
    unsigned short* __restrict__ w2frag,
    unsigned short* __restrict__ w3frag,
    unsigned short* __restrict__ bfragGG,
    float* __restrict__ bgagb)
{
  const int item = blockIdx.x * 256 + threadIdx.x;
  if (item < 512) {                      // conv2 A-frags
    const int tl = item >> 6, lane = item & 63;
    const int mt = tl >> 1, kc = tl & 1;
    const int lr = lane & 15, quad = lane >> 4;
    const int c = mt * 16 + lr;
    const float gs = g2[c] * BN_SCALE;
#pragma unroll
    for (int j = 0; j < 8; ++j) {
      const int k = quad * 8 + j;
      float v;
      if (kc == 0) { const int tap = k >> 4, ci = k & 15; v = w2c[c * 48 + ci * 3 + tap] * gs; }
      else         { v = (k < 16) ? w2c[c * 48 + k * 3 + 2] * gs : 0.f; }
      w2frag[item * 8 + j] = f2bf(v);
    }
  } else if (item < 1664) {              // conv3 A-frags
    const int it = item - 512;
    const int tl = it >> 6, lane = it & 63;
    const int mt = tl / 3, tap = tl - mt * 3;
    const int lr = lane & 15, quad = lane >> 4;
    const int c = mt * 16 + lr;
    const float gs = g3[c] * BN_SCALE;
#pragma unroll
    for (int j = 0; j < 8; ++j) {
      const int ci = quad * 8 + j;
      w3frag[it * 8 + j] = f2bf(w3c[c * 96 + ci * 3 + tap] * gs);
    }
  } else if (item < 19072) {             // Wgagb B-frags
    const int it = item - 1664;
    const int chunk = it >> 8;
    const int rem = it & 255;
    const int nt = rem >> 6;
    const int lane = rem & 63;
    const int lr = lane & 15, quad = lane >> 4;
    const int n = nt * 16 + lr;
    const int off = (n >= 32) ? 32 : 0;
    const int nj = n & 31;
    float w1col[32];
#pragma unroll 8
    for (int q = 0; q < 32; ++q) w1col[q] = w1[(q + off) * 32 + nj];
#pragma unroll
    for (int j = 0; j < 8; ++j) {
      const int k = chunk * 32 + quad * 8 + j;
      float v = 0.f;
      if (k < 2160) {
        const float* fr = fcw + (size_t)k * 32;
#pragma unroll 8
        for (int q = 0; q < 32; ++q) v = fmaf(fr[q], w1col[q], v);
      }
      bfragGG[(size_t)it * 8 + j] = f2bf(v);
    }
  } else if (item < 19136) {             // folded biases
    const int n = item - 19072;
    const int off = (n >= 32) ? 32 : 0;
    const int nj = n & 31;
    float s = (n < 32) ? b1[nj] : 0.f;
    for (int q = 0; q < 32; ++q) s = fmaf(fcb[q], w1[(q + off) * 32 + nj], s);
    bgagb[n] = s;
  }
}

// ---------------------------------------------------------------------------
// fe: wave-autonomous (R0 structure). s2t OVERLAYS s1t (safe: tile nt reads
// rows 16nt..16nt+17 before writing rows <=16nt+15; later tiles read only
// higher rows; DS pipe in-order per wave). leaky applied AFTER pool-max
// (bit-exact, monotone). Arena 6912 B per wave -> 11 blocks (22 waves)/CU.
// ---------------------------------------------------------------------------
__global__ __launch_bounds__(128) void fe_kernel(
    const float* __restrict__ x,
    const float* __restrict__ w1c, const float* __restrict__ b1c,
    const float* __restrict__ g1,  const float* __restrict__ bb1,
    const float* __restrict__ b2c, const float* __restrict__ g2, const float* __restrict__ bb2,
    const float* __restrict__ b3c, const float* __restrict__ g3, const float* __restrict__ bb3,
    const unsigned short* __restrict__ w2frag,
    const unsigned short* __restrict__ w3frag,
    unsigned short* __restrict__ act3)
{
  __shared__ __align__(16) char smem[2 * 6912];
  const int t = threadIdx.x;
  const int wv = t >> 6, lane = t & 63, quad = lane >> 4, lr = lane & 15;
  const int n = blockIdx.x * 2 + wv;

  char* A = smem + wv * 6912;
  unsigned short* buf = (unsigned short*)A;   // s1t: 194r x 16sh / s2t: 98r x 32sh (overlaid)
  float* be2 = (float*)(A + 6272);            // 64
  float* be3 = (float*)(A + 6528);            // 96

  bf16x8 a2[4][2];
#pragma unroll
  for (int mt = 0; mt < 4; ++mt)
#pragma unroll
    for (int kc = 0; kc < 2; ++kc)
      a2[mt][kc] = *(const bf16x8*)(w2frag + ((mt * 2 + kc) * 64 + lane) * 8);

  be2[lane] = b2c[lane] * (g2[lane] * BN_SCALE) + bb2[lane];
  be3[lane] = b3c[lane] * (g3[lane] * BN_SCALE) + bb3[lane];
  if (lane < 32) be3[64 + lane] = b3c[64 + lane] * (g3[64 + lane] * BN_SCALE) + bb3[64 + lane];
  ((unsigned*)buf)[1488 + lane] = 0;          // s1t pad rows 186..193

  const int cp = lane & 7;
  float u[4][3], bbr[4];
#pragma unroll
  for (int d = 0; d < 4; ++d) {
    const int c = cp * 4 + d;
    const float gs = g1[c] * BN_SCALE;
    u[d][0] = w1c[c * 3 + 0] * gs;
    u[d][1] = w1c[c * 3 + 1] * gs;
    u[d][2] = w1c[c * 3 + 2] * gs;
    bbr[d] = b1c[c] * gs + bb1[c];
  }

  // ---- stage 1: conv1+bn+pool+leaky -> buf rows 0..185 (16sh stride) ----
  const float* xr = x + (size_t)n * 375;
  for (int o = lane; o < 1488; o += 64) {
    const int l = o >> 3;
    const int p = 2 * l;
    const float x0 = xr[p], x1 = xr[p + 1], x2 = xr[p + 2], x3 = xr[p + 3];
    unsigned pk = 0;
#pragma unroll
    for (int uu = 0; uu < 2; ++uu) {
      float m = -3.4e38f;
#pragma unroll
      for (int dc = 0; dc < 2; ++dc) {
        const int d = uu * 2 + dc;
        const float v0 = fmaf(x0, u[d][0], fmaf(x1, u[d][1], fmaf(x2, u[d][2], bbr[d])));
        const float v1 = fmaf(x1, u[d][0], fmaf(x2, u[d][1], fmaf(x3, u[d][2], bbr[d])));
        m = fmaxf(m, fmaxf(v0, v1));
      }
      pk |= (unsigned)f2bf(leaky(m)) << (16 * uu);
    }
    ((unsigned*)buf)[l * 8 + cp] = pk;
  }

  float be2r[4][4];
#pragma unroll
  for (int mt = 0; mt < 4; ++mt)
#pragma unroll
    for (int r = 0; r < 4; ++r) be2r[mt][r] = be2[mt * 16 + quad * 4 + r];

  // ---- conv2: 12 n-tiles; reads s1t rows, writes s2t rows (overlaid) ----
#pragma unroll 2
  for (int nt = 0; nt < 12; ++nt) {
    const int nrow = nt * 16 + lr;
    bf16x8 b0 = *(const bf16x8*)(buf + (nrow + (quad >> 1)) * 16 + (quad & 1) * 8);
    bf16x8 b1 = *(const bf16x8*)(buf + (nrow + 2) * 16 + (quad & 1) * 8);
    f32x4 acc[4];
#pragma unroll
    for (int mt = 0; mt < 4; ++mt)
#pragma unroll
      for (int r = 0; r < 4; ++r) acc[mt][r] = be2r[mt][r];
#pragma unroll
    for (int mt = 0; mt < 4; ++mt)
      acc[mt] = __builtin_amdgcn_mfma_f32_16x16x32_bf16(a2[mt][0], b0, acc[mt], 0, 0, 0);
#pragma unroll
    for (int mt = 0; mt < 4; ++mt)
      acc[mt] = __builtin_amdgcn_mfma_f32_16x16x32_bf16(a2[mt][1], b1, acc[mt], 0, 0, 0);
#pragma unroll
    for (int mt = 0; mt < 4; ++mt) {
      float o[4];
#pragma unroll
      for (int r = 0; r < 4; ++r)
        o[r] = fmaxf(acc[mt][r], __shfl_xor(acc[mt][r], 1));
      if ((lr & 1) == 0) {
        const int np = nrow >> 1;
        if (np <= 91) {
          const float m0 = leaky(fmaxf(o[0], o[1]));
          const float m1 = leaky(fmaxf(o[2], o[3]));
          const unsigned pk = (unsigned)f2bf(m0) | ((unsigned)f2bf(m1) << 16);
          ((unsigned*)buf)[np * 16 + mt * 4 + quad] = pk;
        }
      }
    }
  }

  // ---- zero s2t pad rows 92..97 (safe: conv2 done with s1t tail) ----
  ((unsigned*)buf)[1472 + lane] = 0;
  if (lane < 32) ((unsigned*)buf)[1536 + lane] = 0;

  // ---- conv3: 6x6 tiles x 3 tap-MFMAs; epilogue -> act3 (global) ----
  unsigned short* actr = act3 + (size_t)n * 2176;
  for (int mt = 0; mt < 6; ++mt) {
    bf16x8 a3[3];
#pragma unroll
    for (int tap = 0; tap < 3; ++tap)
      a3[tap] = *(const bf16x8*)(w3frag + ((mt * 3 + tap) * 64 + lane) * 8);
    float be3r[4];
#pragma unroll
    for (int r = 0; r < 4; ++r) be3r[r] = be3[mt * 16 + quad * 4 + r];
#pragma unroll
    for (int nt = 0; nt < 6; ++nt) {
      const int nrow = nt * 16 + lr;
      f32x4 acc;
#pragma unroll
      for (int r = 0; r < 4; ++r) acc[r] = be3r[r];
#pragma unroll
      for (int tap = 0; tap < 3; ++tap) {
        bf16x8 b = *(const bf16x8*)(buf + (nrow + tap) * 32 + quad * 8);
        acc = __builtin_amdgcn_mfma_f32_16x16x32_bf16(a3[tap], b, acc, 0, 0, 0);
      }
      float o[4];
#pragma unroll
      for (int r = 0; r < 4; ++r)
        o[r] = fmaxf(acc[r], __shfl_xor(acc[r], 1));
      if ((lr & 1) == 0) {
        const int np = nrow >> 1;
        if (np <= 44) {
          const int mp = mt * 8 + quad * 2;
          actr[mp * 45 + np] = f2bf(leaky(fmaxf(o[0], o[1])));
          actr[(mp + 1) * 45 + np] = f2bf(leaky(fmaxf(o[2], o[3])));
        }
      }
    }
  }
  if (lane < 16) actr[2160 + lane] = 0;
}

// ---------------------------------------------------------------------------
// gagb: 254 blocks x 16 rows; 4 waves split K (17 chunks each); LDS reduce.
// ---------------------------------------------------------------------------
__global__ __launch_bounds__(256) void gagb_kernel(
    const unsigned short* __restrict__ act3,
    const unsigned short* __restrict__ bfragGG,
    const float* __restrict__ bgagb,
    float* __restrict__ Ga, float* __restrict__ Gb)
{
  __shared__ f32x4 sred[3][4][64];
  const int t = threadIdx.x;
  const int wv = t >> 6, lane = t & 63, quad = lane >> 4, lr = lane & 15;
  const int m0 = blockIdx.x * 16;
  const int arow = min(m0 + lr, 4049);

  f32x4 acc[4] = {};
  const int c0 = wv * 17;
  for (int chunk = c0; chunk < c0 + 17; ++chunk) {
    const bf16x8 a = *(const bf16x8*)(act3 + (size_t)arow * 2176 + chunk * 32 + quad * 8);
#pragma unroll
    for (int nt = 0; nt < 4; ++nt) {
      const bf16x8 b = *(const bf16x8*)(bfragGG + ((size_t)(chunk * 4 + nt) * 64 + lane) * 8);
      acc[nt] = __builtin_amdgcn_mfma_f32_16x16x32_bf16(a, b, acc[nt], 0, 0, 0);
    }
  }
  if (wv > 0) {
#pragma unroll
    for (int nt = 0; nt < 4; ++nt) sred[wv - 1][nt][lane] = acc[nt];
  }
  __syncthreads();
  if (wv == 0) {
#pragma unroll
    for (int nt = 0; nt < 4; ++nt) {
      f32x4 s = acc[nt];
#pragma unroll
      for (int q = 0; q < 3; ++q) {
        const f32x4 o = sred[q][nt][lane];
#pragma unroll
        for (int r = 0; r < 4; ++r) s[r] += o[r];
      }
      const int col = nt * 16 + lr;
      const float bias = bgagb[col];
#pragma unroll
      for (int r = 0; r < 4; ++r) {
        const int row = m0 + quad * 4 + r;
        if (row < 4050) {
          const float v = s[r] + bias;
          if (col < 32) Ga[row * 32 + col] = v;
          else          Gb[row * 32 + (col - 32)] = v;
        }
      }
    }
  }
}

// ---------------------------------------------------------------------------
// sim: 960 blocks = 30 subjects x 32 chunks; writes f32 subjectsT[p][b].
// ---------------------------------------------------------------------------
__global__ __launch_bounds__(256) void sim_kernel(
    const float* __restrict__ Ga, const float* __restrict__ Gb,
    const float* __restrict__ w2, const float* __restrict__ b2,
    const float* __restrict__ w3, const float* __restrict__ b3,
    const float* __restrict__ w4, const float* __restrict__ b4,
    float* __restrict__ subjectsT)
{
  __shared__ float sGa[135 * 36];
  __shared__ float sGb[135 * 36];
  __shared__ float sw2[512], sw3[128], sw4[8];
  __shared__ float sb2[16], sb3[8], sb4v[1];

  const int t = threadIdx.x;
  const int b = blockIdx.x >> 5;
  const int c = blockIdx.x & 31;

  for (int i = t; i < 4320; i += 256) {
    const int r = i >> 5, col = i & 31;
    sGa[r * 36 + col] = Ga[b * 4320 + i];
    sGb[r * 36 + col] = Gb[b * 4320 + i];
  }
  for (int i = t; i < 512; i += 256) sw2[i] = w2[i];
  if (t < 128) sw3[t] = w3[t];
  if (t < 8) sw4[t] = w4[t];
  if (t < 16) sb2[t] = b2[t];
  if (t < 8) sb3[t] = b3[t];
  if (t == 0) sb4v[0] = b4[0];
  __syncthreads();

  const int pend = min(9045, (c + 1) * 283);
  for (int p = c * 283 + t; p < pend; p += 256) {
    int i = (int)((269.0f - sqrtf((float)(72361 - 8 * p))) * 0.5f);
    i = max(0, min(133, i));
    while (134 * (i + 1) - ((i + 1) * i) / 2 <= p) ++i;
    while (134 * i - (i * (i - 1)) / 2 > p) --i;
    const int j = i + 1 + (p - (134 * i - (i * (i - 1)) / 2));

    float h1[32];
#pragma unroll
    for (int q = 0; q < 8; ++q) {
      const float4 va = *(const float4*)(&sGa[i * 36 + 4 * q]);
      const float4 vb = *(const float4*)(&sGb[j * 36 + 4 * q]);
      h1[4 * q + 0] = fmaxf(va.x + vb.x, 0.f);
      h1[4 * q + 1] = fmaxf(va.y + vb.y, 0.f);
      h1[4 * q + 2] = fmaxf(va.z + vb.z, 0.f);
      h1[4 * q + 3] = fmaxf(va.w + vb.w, 0.f);
    }

    float h2[16];
#pragma unroll
    for (int jj = 0; jj < 16; ++jj) h2[jj] = sb2[jj];
#pragma unroll 8
    for (int ii = 0; ii < 32; ++ii) {
      const float av = h1[ii];
      const float4* wr = reinterpret_cast<const float4*>(&sw2[ii * 16]);
#pragma unroll
      for (int r = 0; r < 4; ++r) {
        float4 w = wr[r];
        h2[4 * r + 0] = fmaf(av, w.x, h2[4 * r + 0]);
        h2[4 * r + 1] = fmaf(av, w.y, h2[4 * r + 1]);
        h2[4 * r + 2] = fmaf(av, w.z, h2[4 * r + 2]);
        h2[4 * r + 3] = fmaf(av, w.w, h2[4 * r + 3]);
      }
    }
#pragma unroll
    for (int jj = 0; jj < 16; ++jj) h2[jj] = fmaxf(h2[jj], 0.f);

    float h3[8];
#pragma unroll
    for (int jj = 0; jj < 8; ++jj) h3[jj] = sb3[jj];
#pragma unroll
    for (int ii = 0; ii < 16; ++ii) {
      const float av = h2[ii];
      const float4* wr = reinterpret_cast<const float4*>(&sw3[ii * 8]);
#pragma unroll
      for (int r = 0; r < 2; ++r) {
        float4 w = wr[r];
        h3[4 * r + 0] = fmaf(av, w.x, h3[4 * r + 0]);
        h3[4 * r + 1] = fmaf(av, w.y, h3[4 * r + 1]);
        h3[4 * r + 2] = fmaf(av, w.z, h3[4 * r + 2]);
        h3[4 * r + 3] = fmaf(av, w.w, h3[4 * r + 3]);
      }
    }
#pragma unroll
    for (int jj = 0; jj < 8; ++jj) h3[jj] = fmaxf(h3[jj], 0.f);

    float z = sb4v[0];
#pragma unroll
    for (int ii = 0; ii < 8; ++ii) z = fmaf(h3[ii], sw4[ii], z);

    const float az = fabsf(z);
    const float e = __expf(-2.f * az);
    const float rr = (1.f - e) / (1.f + e);
    const float val = copysignf(rr, z);

    subjectsT[(size_t)p * 32 + b] = val;
  }
}

// ---------------------------------------------------------------------------
// c1 v4: software-pipelined fp32 GEMV batch. R3/R4 both stalled at ~65us
// because only ONE load pair was in flight per wave (VALUBusy 7%, pure
// latency serialization over 142 k-iters). v4 processes k in chunks of 4
// with next-chunk loads issued BEFORE current-chunk FMAs: 8 float4 loads
// (4KB/wave) in flight -> latency amortized 4x and overlapped with compute.
// kn is block-uniform -> guards are scalar branches. ~90 VGPR, no LDS.
// Same part layout -> tail_a unchanged.
// ---------------------------------------------------------------------------
__global__ __launch_bounds__(256) void c1_kernel(
    const float* __restrict__ subjectsT,
    const float* __restrict__ cw1,
    float* __restrict__ part)
{
  const int t = threadIdx.x;
  const int cg = blockIdx.x & 7;
  const int kg = blockIdx.x >> 3;
  const int cq = t & 31;                // 32 col-quads -> 128 cols
  const int mg = t >> 5;                // 0..7 m-group (4 subjects; mg7 has 2)
  const int col = cg * 128 + cq * 4;
  const int mbase = mg * 4;
  const int nm = (mg == 7) ? 2 : 4;

  const int k0 = kg * 142;
  const int kn = min(9045 - k0, 142);   // block-uniform

  f32x4 acc0 = {0.f, 0.f, 0.f, 0.f};
  f32x4 acc1 = {0.f, 0.f, 0.f, 0.f};
  f32x4 acc2 = {0.f, 0.f, 0.f, 0.f};
  f32x4 acc3 = {0.f, 0.f, 0.f, 0.f};

  const float* wp = cw1 + (size_t)k0 * 1024 + col;
  const float* sp = subjectsT + (size_t)k0 * 32 + mbase;

  float4 w[4], s[4];
  float4 wn[4], sn[4];

  // prologue: load chunk 0
#pragma unroll
  for (int i = 0; i < 4; ++i) {
    if (i < kn) {
      w[i] = *(const float4*)(wp + (size_t)i * 1024);
      s[i] = *(const float4*)(sp + (size_t)i * 32);
    }
  }

  for (int kk = 0; kk < kn; kk += 4) {
    const int rem = kn - kk;            // elements in current chunk (>=1)
    const int nxt = kn - kk - 4;        // elements in next chunk (may be <0)
    // issue next chunk's loads first (stay in flight across the FMAs)
#pragma unroll
    for (int i = 0; i < 4; ++i) {
      if (i < nxt) {
        wn[i] = *(const float4*)(wp + (size_t)(kk + 4 + i) * 1024);
        sn[i] = *(const float4*)(sp + (size_t)(kk + 4 + i) * 32);
      }
    }
    // consume current chunk
#pragma unroll
    for (int i = 0; i < 4; ++i) {
      if (i < rem) {
        const float4 wi = w[i];
        const float4 si = s[i];
        acc0[0] = fmaf(si.x, wi.x, acc0[0]); acc0[1] = fmaf(si.x, wi.y, acc0[1]);
        acc0[2] = fmaf(si.x, wi.z, acc0[2]); acc0[3] = fmaf(si.x, wi.w, acc0[3]);
        acc1[0] = fmaf(si.y, wi.x, acc1[0]); acc1[1] = fmaf(si.y, wi.y, acc1[1]);
        acc1[2] = fmaf(si.y, wi.z, acc1[2]); acc1[3] = fmaf(si.y, wi.w, acc1[3]);
        acc2[0] = fmaf(si.z, wi.x, acc2[0]); acc2[1] = fmaf(si.z, wi.y, acc2[1]);
        acc2[2] = fmaf(si.z, wi.z, acc2[2]); acc2[3] = fmaf(si.z, wi.w, acc2[3]);
        acc3[0] = fmaf(si.w, wi.x, acc3[0]); acc3[1] = fmaf(si.w, wi.y, acc3[1]);
        acc3[2] = fmaf(si.w, wi.z, acc3[2]); acc3[3] = fmaf(si.w, wi.w, acc3[3]);
      }
    }
    // rotate
#pragma unroll
    for (int i = 0; i < 4; ++i) { w[i] = wn[i]; s[i] = sn[i]; }
  }

  *(f32x4*)(&part[(size_t)((mbase + 0) * 64 + kg) * 1024 + col]) = acc0;
  if (nm > 1) *(f32x4*)(&part[(size_t)((mbase + 1) * 64 + kg) * 1024 + col]) = acc1;
  if (nm > 2) *(f32x4*)(&part[(size_t)((mbase + 2) * 64 + kg) * 1024 + col]) = acc2;
  if (nm > 3) *(f32x4*)(&part[(size_t)((mbase + 3) * 64 + kg) * 1024 + col]) = acc3;
}

// ---------------------------------------------------------------------------
// tail_a: reduce 64 partials + rrelu -> act1[30][1024]. 120 blocks.
// ---------------------------------------------------------------------------
__global__ __launch_bounds__(256) void tail_a_kernel(
    const float* __restrict__ part,
    const float* __restrict__ cb1,
    float* __restrict__ act1)
{
  const int r = blockIdx.x >> 2;
  const int cg = blockIdx.x & 3;
  const int j = cg * 256 + threadIdx.x;
  float s = cb1[j];
  const float* pp = part + (size_t)r * 64 * 1024 + j;
#pragma unroll 8
  for (int q = 0; q < 64; ++q) s += pp[q * 1024];
  act1[r * 1024 + j] = s >= 0.f ? s : RRELU_SLOPE * s;
}

// ---------------------------------------------------------------------------
// tail_b: GEMM2 (1024->256) + relu -> act2. 240 blocks.
// ---------------------------------------------------------------------------
__global__ __launch_bounds__(256) void tail_b_kernel(
    const float* __restrict__ act1,
    const float* __restrict__ w2, const float* __restrict__ cb2,
    float* __restrict__ act2)
{
  __shared__ float sa[1024];
  __shared__ float sp[256];
  const int r = blockIdx.x >> 3;
  const int cg = blockIdx.x & 7;
  const int t = threadIdx.x;
  const int c = t & 31;
  const int ks = t >> 5;
  const int col = cg * 32 + c;

  for (int i = t; i < 1024; i += 256) sa[i] = act1[r * 1024 + i];
  __syncthreads();

  float acc = 0.f;
  const int k0 = ks * 128;
  for (int kk = k0; kk < k0 + 128; kk += 4) {
    const float4 a = *reinterpret_cast<const float4*>(&sa[kk]);
    acc = fmaf(a.x, w2[(kk + 0) * 256 + col], acc);
    acc = fmaf(a.y, w2[(kk + 1) * 256 + col], acc);
    acc = fmaf(a.z, w2[(kk + 2) * 256 + col], acc);
    acc = fmaf(a.w, w2[(kk + 3) * 256 + col], acc);
  }
  sp[t] = acc;
  __syncthreads();
  if (t < 32) {
    float s = cb2[col];
#pragma unroll
    for (int q = 0; q < 8; ++q) s += sp[q * 32 + t];
    act2[r * 256 + cg * 32 + t] = fmaxf(s, 0.f);
  }
}

// ---------------------------------------------------------------------------
// tail_c: GEMM3 (256->64, 4-way k-split) + GEMM4 (64->3) + log_softmax.
// ---------------------------------------------------------------------------
__global__ __launch_bounds__(256) void tail_c_kernel(
    const float* __restrict__ act2,
    const float* __restrict__ w3, const float* __restrict__ cb3,
    const float* __restrict__ w4, const float* __restrict__ cb4,
    float* __restrict__ out)
{
  __shared__ float sa[256];
  __shared__ float sp[256];
  __shared__ float sc3[64];
  __shared__ float slg[3];
  const int r = blockIdx.x, t = threadIdx.x;
  const int c = t & 63;
  const int ks = t >> 6;

  sa[t] = act2[r * 256 + t];
  __syncthreads();
  {
    float acc = 0.f;
    const int k0 = ks * 64;
#pragma unroll 4
    for (int kk = k0; kk < k0 + 64; ++kk)
      acc = fmaf(sa[kk], w3[kk * 64 + c], acc);
    sp[t] = acc;
  }
  __syncthreads();
  if (t < 64) {
    const float s = cb3[t] + sp[t] + sp[t + 64] + sp[t + 128] + sp[t + 192];
    sc3[t] = fmaxf(s, 0.f);
  }
  __syncthreads();
  if (t < 3) {
    float acc = cb4[t];
#pragma unroll
    for (int kk = 0; kk < 64; ++kk) acc = fmaf(sc3[kk], w4[kk * 3 + t], acc);
    slg[t] = acc;
  }
  __syncthreads();
  if (t == 0) {
    float m = fmaxf(slg[0], fmaxf(slg[1], slg[2]));
    float se = __expf(slg[0] - m) + __expf(slg[1] - m) + __expf(slg[2] - m);
    float lse = m + logf(se);
    out[r * 3 + 0] = slg[0] - lse;
    out[r * 3 + 1] = slg[1] - lse;
    out[r * 3 + 2] = slg[2] - lse;
  }
}

extern "C" void kernel_launch(void* const* d_in, const int* in_sizes, int n_in,
                              void* d_out, int out_size, void* d_ws, size_t ws_size,
                              hipStream_t stream) {
  const float* x    = (const float*)d_in[0];
  const float* w1c  = (const float*)d_in[1];
  const float* b1c  = (const float*)d_in[2];
  const float* g1   = (const float*)d_in[3];
  const float* bb1  = (const float*)d_in[4];
  const float* w2c  = (const float*)d_in[5];
  const float* b2c  = (const float*)d_in[6];
  const float* g2   = (const float*)d_in[7];
  const float* bb2  = (const float*)d_in[8];
  const float* w3c  = (const float*)d_in[9];
  const float* b3c  = (const float*)d_in[10];
  const float* g3   = (const float*)d_in[11];
  const float* bb3  = (const float*)d_in[12];
  const float* fcw  = (const float*)d_in[13];
  const float* fcb  = (const float*)d_in[14];
  const float* sw1  = (const float*)d_in[15];
  const float* sb1  = (const float*)d_in[16];
  const float* sw2  = (const float*)d_in[17];
  const float* sb2  = (const float*)d_in[18];
  const float* sw3  = (const float*)d_in[19];
  const float* sb3  = (const float*)d_in[20];
  const float* sw4  = (const float*)d_in[21];
  const float* sb4  = (const float*)d_in[22];
  const float* cw1  = (const float*)d_in[23];
  const float* cb1  = (const float*)d_in[24];
  const float* cw2  = (const float*)d_in[25];
  const float* cb2  = (const float*)d_in[26];
  const float* cw3  = (const float*)d_in[27];
  const float* cb3  = (const float*)d_in[28];
  const float* cw4  = (const float*)d_in[29];
  const float* cb4  = (const float*)d_in[30];

  float* ws = (float*)d_ws;
  float* Ga    = ws;                     // 129600
  float* Gb    = ws + 129600;            // -> 259200
  float* part  = ws + 259200;            // 30*64*1024 -> 2225280
  float* bgagb = ws + 2225280;           // 64 -> 2225344
  float* act1  = ws + 2225344;           // 30720 -> 2256064
  float* act2  = ws + 2256064;           // 7680 -> 2263744
  float* subjectsT = ws + 2263744;       // 9045*32 = 289440 -> 2553184
  unsigned short* wsu = (unsigned short*)(ws + 2553184);
  unsigned short* w2frag    = wsu;             // 4096 sh
  unsigned short* w3frag    = wsu + 4096;      // -> 13312
  unsigned short* bfragGG   = wsu + 13312;     // -> 152576
  unsigned short* act3      = wsu + 152576;    // -> 8965376 (4050*2176)

  setup_kernel<<<75, 256, 0, stream>>>(w2c, g2, w3c, g3, fcw, fcb, sw1, sb1,
                                       w2frag, w3frag, bfragGG, bgagb);
  fe_kernel<<<2025, 128, 0, stream>>>(x, w1c, b1c, g1, bb1, b2c, g2, bb2,
                                      b3c, g3, bb3, w2frag, w3frag, act3);
  gagb_kernel<<<254, 256, 0, stream>>>(act3, bfragGG, bgagb, Ga, Gb);
  sim_kernel<<<960, 256, 0, stream>>>(Ga, Gb, sw2, sb2, sw3, sb3, sw4, sb4, subjectsT);
  c1_kernel<<<512, 256, 0, stream>>>(subjectsT, cw1, part);
  tail_a_kernel<<<120, 256, 0, stream>>>(part, cb1, act1);
  tail_b_kernel<<<240, 256, 0, stream>>>(act1, cw2, cb2, act2);
  tail_c_kernel<<<30, 256, 0, stream>>>(act2, cw3, cb3, cw4, cb4, (float*)d_out);
}

// Round 6
// 260.418 us; speedup vs baseline: 1.1345x; 1.0669x over previous
//
#include <hip/hip_runtime.h>
#include <math.h>

#define BN_SCALE 0.99999500003749967f
#define RRELU_SLOPE 0.22916666666666666f

static __device__ __forceinline__ float leaky(float v) { return v > 0.f ? v : 0.01f * v; }

typedef __attribute__((ext_vector_type(8))) short bf16x8;
typedef __attribute__((ext_vector_type(4))) float f32x4;

static __device__ __forceinline__ unsigned short f2bf(float f) {
  unsigned u = __builtin_bit_cast(unsigned, f);
  u = (u + 0x7FFFu + ((u >> 16) & 1u)) >> 16;
  return (unsigned short)u;
}

// ---------------------------------------------------------------------------
// setup (merged prep + w1t, R0-proven): blocks 0..2271 transpose w1 -> w1T
// bf16; blocks 2272.. do conv frags, Wgagb B-frags, folded biases, subjectsA
// zero. (R3-R5's fp32-direct c1 never beat this path: latency-serial GEMV
// stuck at 50-66us vs transpose+MFMA ~= 17-20us combined.)
// ---------------------------------------------------------------------------
__global__ __launch_bounds__(256) void setup_kernel(
    const float* __restrict__ w2c, const float* __restrict__ g2,
    const float* __restrict__ w3c, const float* __restrict__ g3,
    const float* __restrict__ fcw, const float* __restrict__ fcb,
    const float* __restrict__ w1,  const float* __restrict__ b1,
    const float* __restrict__ cw1,
    unsigned short* __restrict__ w2frag,
    unsigned short* __restrict__ w3frag,
    unsigned short* __restrict__ bfragGG,
    float* __restrict__ bgagb,
    unsigned short* __restrict__ subjectsA,
    unsigned short* __restrict__ w1T)
{
  __shared__ float tile[64][65];
  const int t = threadIdx.x;
  if (blockIdx.x < 2272) {               // ---- w1 transpose -> w1T ----
    const int kt = blockIdx.x >> 4;
    const int ntb = blockIdx.x & 15;
    const int k0 = kt * 64, n0 = ntb * 64;
#pragma unroll 4
    for (int i = 0; i < 16; ++i) {
      const int idx = i * 256 + t;
      const int kk = idx >> 6, nn = idx & 63;
      const int k = k0 + kk;
      tile[kk][nn] = (k < 9045) ? cw1[(size_t)k * 1024 + n0 + nn] : 0.f;
    }
    __syncthreads();
#pragma unroll 4
    for (int i = 0; i < 8; ++i) {
      const int idx = i * 256 + t;
      const int nn = idx >> 5;
      const int kp = (idx & 31) * 2;
      const unsigned lo = f2bf(tile[kp][nn]);
      const unsigned hi = f2bf(tile[kp + 1][nn]);
      ((unsigned*)w1T)[(size_t)(n0 + nn) * 4544 + (k0 >> 1) + (idx & 31)] = lo | (hi << 16);
    }
    return;
  }
  const int item = (blockIdx.x - 2272) * 256 + t;
  if (item < 512) {                      // conv2 A-frags
    const int tl = item >> 6, lane = item & 63;
    const int mt = tl >> 1, kc = tl & 1;
    const int lr = lane & 15, quad = lane >> 4;
    const int c = mt * 16 + lr;
    const float gs = g2[c] * BN_SCALE;
#pragma unroll
    for (int j = 0; j < 8; ++j) {
      const int k = quad * 8 + j;
      float v;
      if (kc == 0) { const int tap = k >> 4, ci = k & 15; v = w2c[c * 48 + ci * 3 + tap] * gs; }
      else         { v = (k < 16) ? w2c[c * 48 + k * 3 + 2] * gs : 0.f; }
      w2frag[item * 8 + j] = f2bf(v);
    }
  } else if (item < 1664) {              // conv3 A-frags
    const int it = item - 512;
    const int tl = it >> 6, lane = it & 63;
    const int mt = tl / 3, tap = tl - mt * 3;
    const int lr = lane & 15, quad = lane >> 4;
    const int c = mt * 16 + lr;
    const float gs = g3[c] * BN_SCALE;
#pragma unroll
    for (int j = 0; j < 8; ++j) {
      const int ci = quad * 8 + j;
      w3frag[it * 8 + j] = f2bf(w3c[c * 96 + ci * 3 + tap] * gs);
    }
  } else if (item < 19072) {             // Wgagb B-frags
    const int it = item - 1664;
    const int chunk = it >> 8;
    const int rem = it & 255;
    const int nt = rem >> 6;
    const int lane = rem & 63;
    const int lr = lane & 15, quad = lane >> 4;
    const int n = nt * 16 + lr;
    const int off = (n >= 32) ? 32 : 0;
    const int nj = n & 31;
    float w1col[32];
#pragma unroll 8
    for (int q = 0; q < 32; ++q) w1col[q] = w1[(q + off) * 32 + nj];
#pragma unroll
    for (int j = 0; j < 8; ++j) {
      const int k = chunk * 32 + quad * 8 + j;
      float v = 0.f;
      if (k < 2160) {
        const float* fr = fcw + (size_t)k * 32;
#pragma unroll 8
        for (int q = 0; q < 32; ++q) v = fmaf(fr[q], w1col[q], v);
      }
      bfragGG[(size_t)it * 8 + j] = f2bf(v);
    }
  } else if (item < 19136) {             // folded biases
    const int n = item - 19072;
    const int off = (n >= 32) ? 32 : 0;
    const int nj = n & 31;
    float s = (n < 32) ? b1[nj] : 0.f;
    for (int q = 0; q < 32; ++q) s = fmaf(fcb[q], w1[(q + off) * 32 + nj], s);
    bgagb[n] = s;
  } else if (item < 55360) {             // zero subjectsA (283*1024 shorts)
    const int idx = item - 19136;
    uint4 z = {0u, 0u, 0u, 0u};
    ((uint4*)subjectsA)[idx] = z;
  }
}

// ---------------------------------------------------------------------------
// fe: wave-autonomous (R0 structure). s2t OVERLAYS s1t (safe: tile nt reads
// rows 16nt..16nt+17 before writing rows <=16nt+15; later tiles read only
// higher rows; DS pipe in-order per wave). leaky applied AFTER pool-max
// (bit-exact, monotone; measured 56.9 -> 52.2us). Arena 6912 B per wave.
// ---------------------------------------------------------------------------
__global__ __launch_bounds__(128) void fe_kernel(
    const float* __restrict__ x,
    const float* __restrict__ w1c, const float* __restrict__ b1c,
    const float* __restrict__ g1,  const float* __restrict__ bb1,
    const float* __restrict__ b2c, const float* __restrict__ g2, const float* __restrict__ bb2,
    const float* __restrict__ b3c, const float* __restrict__ g3, const float* __restrict__ bb3,
    const unsigned short* __restrict__ w2frag,
    const unsigned short* __restrict__ w3frag,
    unsigned short* __restrict__ act3)
{
  __shared__ __align__(16) char smem[2 * 6912];
  const int t = threadIdx.x;
  const int wv = t >> 6, lane = t & 63, quad = lane >> 4, lr = lane & 15;
  const int n = blockIdx.x * 2 + wv;

  char* A = smem + wv * 6912;
  unsigned short* buf = (unsigned short*)A;   // s1t: 194r x 16sh / s2t: 98r x 32sh (overlaid)
  float* be2 = (float*)(A + 6272);            // 64
  float* be3 = (float*)(A + 6528);            // 96

  bf16x8 a2[4][2];
#pragma unroll
  for (int mt = 0; mt < 4; ++mt)
#pragma unroll
    for (int kc = 0; kc < 2; ++kc)
      a2[mt][kc] = *(const bf16x8*)(w2frag + ((mt * 2 + kc) * 64 + lane) * 8);

  be2[lane] = b2c[lane] * (g2[lane] * BN_SCALE) + bb2[lane];
  be3[lane] = b3c[lane] * (g3[lane] * BN_SCALE) + bb3[lane];
  if (lane < 32) be3[64 + lane] = b3c[64 + lane] * (g3[64 + lane] * BN_SCALE) + bb3[64 + lane];
  ((unsigned*)buf)[1488 + lane] = 0;          // s1t pad rows 186..193

  const int cp = lane & 7;
  float u[4][3], bbr[4];
#pragma unroll
  for (int d = 0; d < 4; ++d) {
    const int c = cp * 4 + d;
    const float gs = g1[c] * BN_SCALE;
    u[d][0] = w1c[c * 3 + 0] * gs;
    u[d][1] = w1c[c * 3 + 1] * gs;
    u[d][2] = w1c[c * 3 + 2] * gs;
    bbr[d] = b1c[c] * gs + bb1[c];
  }

  // ---- stage 1: conv1+bn+pool+leaky -> buf rows 0..185 (16sh stride) ----
  const float* xr = x + (size_t)n * 375;
  for (int o = lane; o < 1488; o += 64) {
    const int l = o >> 3;
    const int p = 2 * l;
    const float x0 = xr[p], x1 = xr[p + 1], x2 = xr[p + 2], x3 = xr[p + 3];
    unsigned pk = 0;
#pragma unroll
    for (int uu = 0; uu < 2; ++uu) {
      float m = -3.4e38f;
#pragma unroll
      for (int dc = 0; dc < 2; ++dc) {
        const int d = uu * 2 + dc;
        const float v0 = fmaf(x0, u[d][0], fmaf(x1, u[d][1], fmaf(x2, u[d][2], bbr[d])));
        const float v1 = fmaf(x1, u[d][0], fmaf(x2, u[d][1], fmaf(x3, u[d][2], bbr[d])));
        m = fmaxf(m, fmaxf(v0, v1));
      }
      pk |= (unsigned)f2bf(leaky(m)) << (16 * uu);
    }
    ((unsigned*)buf)[l * 8 + cp] = pk;
  }

  float be2r[4][4];
#pragma unroll
  for (int mt = 0; mt < 4; ++mt)
#pragma unroll
    for (int r = 0; r < 4; ++r) be2r[mt][r] = be2[mt * 16 + quad * 4 + r];

  // ---- conv2: 12 n-tiles; reads s1t rows, writes s2t rows (overlaid) ----
#pragma unroll 2
  for (int nt = 0; nt < 12; ++nt) {
    const int nrow = nt * 16 + lr;
    bf16x8 b0 = *(const bf16x8*)(buf + (nrow + (quad >> 1)) * 16 + (quad & 1) * 8);
    bf16x8 b1 = *(const bf16x8*)(buf + (nrow + 2) * 16 + (quad & 1) * 8);
    f32x4 acc[4];
#pragma unroll
    for (int mt = 0; mt < 4; ++mt)
#pragma unroll
      for (int r = 0; r < 4; ++r) acc[mt][r] = be2r[mt][r];
#pragma unroll
    for (int mt = 0; mt < 4; ++mt)
      acc[mt] = __builtin_amdgcn_mfma_f32_16x16x32_bf16(a2[mt][0], b0, acc[mt], 0, 0, 0);
#pragma unroll
    for (int mt = 0; mt < 4; ++mt)
      acc[mt] = __builtin_amdgcn_mfma_f32_16x16x32_bf16(a2[mt][1], b1, acc[mt], 0, 0, 0);
#pragma unroll
    for (int mt = 0; mt < 4; ++mt) {
      float o[4];
#pragma unroll
      for (int r = 0; r < 4; ++r)
        o[r] = fmaxf(acc[mt][r], __shfl_xor(acc[mt][r], 1));
      if ((lr & 1) == 0) {
        const int np = nrow >> 1;
        if (np <= 91) {
          const float m0 = leaky(fmaxf(o[0], o[1]));
          const float m1 = leaky(fmaxf(o[2], o[3]));
          const unsigned pk = (unsigned)f2bf(m0) | ((unsigned)f2bf(m1) << 16);
          ((unsigned*)buf)[np * 16 + mt * 4 + quad] = pk;
        }
      }
    }
  }

  // ---- zero s2t pad rows 92..97 (safe: conv2 done with s1t tail) ----
  ((unsigned*)buf)[1472 + lane] = 0;
  if (lane < 32) ((unsigned*)buf)[1536 + lane] = 0;

  // ---- conv3: 6x6 tiles x 3 tap-MFMAs; epilogue -> act3 (global) ----
  unsigned short* actr = act3 + (size_t)n * 2176;
  for (int mt = 0; mt < 6; ++mt) {
    bf16x8 a3[3];
#pragma unroll
    for (int tap = 0; tap < 3; ++tap)
      a3[tap] = *(const bf16x8*)(w3frag + ((mt * 3 + tap) * 64 + lane) * 8);
    float be3r[4];
#pragma unroll
    for (int r = 0; r < 4; ++r) be3r[r] = be3[mt * 16 + quad * 4 + r];
#pragma unroll
    for (int nt = 0; nt < 6; ++nt) {
      const int nrow = nt * 16 + lr;
      f32x4 acc;
#pragma unroll
      for (int r = 0; r < 4; ++r) acc[r] = be3r[r];
#pragma unroll
      for (int tap = 0; tap < 3; ++tap) {
        bf16x8 b = *(const bf16x8*)(buf + (nrow + tap) * 32 + quad * 8);
        acc = __builtin_amdgcn_mfma_f32_16x16x32_bf16(a3[tap], b, acc, 0, 0, 0);
      }
      float o[4];
#pragma unroll
      for (int r = 0; r < 4; ++r)
        o[r] = fmaxf(acc[r], __shfl_xor(acc[r], 1));
      if ((lr & 1) == 0) {
        const int np = nrow >> 1;
        if (np <= 44) {
          const int mp = mt * 8 + quad * 2;
          actr[mp * 45 + np] = f2bf(leaky(fmaxf(o[0], o[1])));
          actr[(mp + 1) * 45 + np] = f2bf(leaky(fmaxf(o[2], o[3])));
        }
      }
    }
  }
  if (lane < 16) actr[2160 + lane] = 0;
}

// ---------------------------------------------------------------------------
// gagb: 254 blocks x 16 rows; 4 waves split K (17 chunks each); LDS reduce.
// ---------------------------------------------------------------------------
__global__ __launch_bounds__(256) void gagb_kernel(
    const unsigned short* __restrict__ act3,
    const unsigned short* __restrict__ bfragGG,
    const float* __restrict__ bgagb,
    float* __restrict__ Ga, float* __restrict__ Gb)
{
  __shared__ f32x4 sred[3][4][64];
  const int t = threadIdx.x;
  const int wv = t >> 6, lane = t & 63, quad = lane >> 4, lr = lane & 15;
  const int m0 = blockIdx.x * 16;
  const int arow = min(m0 + lr, 4049);

  f32x4 acc[4] = {};
  const int c0 = wv * 17;
  for (int chunk = c0; chunk < c0 + 17; ++chunk) {
    const bf16x8 a = *(const bf16x8*)(act3 + (size_t)arow * 2176 + chunk * 32 + quad * 8);
#pragma unroll
    for (int nt = 0; nt < 4; ++nt) {
      const bf16x8 b = *(const bf16x8*)(bfragGG + ((size_t)(chunk * 4 + nt) * 64 + lane) * 8);
      acc[nt] = __builtin_amdgcn_mfma_f32_16x16x32_bf16(a, b, acc[nt], 0, 0, 0);
    }
  }
  if (wv > 0) {
#pragma unroll
    for (int nt = 0; nt < 4; ++nt) sred[wv - 1][nt][lane] = acc[nt];
  }
  __syncthreads();
  if (wv == 0) {
#pragma unroll
    for (int nt = 0; nt < 4; ++nt) {
      f32x4 s = acc[nt];
#pragma unroll
      for (int q = 0; q < 3; ++q) {
        const f32x4 o = sred[q][nt][lane];
#pragma unroll
        for (int r = 0; r < 4; ++r) s[r] += o[r];
      }
      const int col = nt * 16 + lr;
      const float bias = bgagb[col];
#pragma unroll
      for (int r = 0; r < 4; ++r) {
        const int row = m0 + quad * 4 + r;
        if (row < 4050) {
          const float v = s[r] + bias;
          if (col < 32) Ga[row * 32 + col] = v;
          else          Gb[row * 32 + (col - 32)] = v;
        }
      }
    }
  }
}

// ---------------------------------------------------------------------------
// sim: 960 blocks = 30 subjects x 32 chunks; writes bf16 MFMA A-fragments.
// ---------------------------------------------------------------------------
__global__ __launch_bounds__(256) void sim_kernel(
    const float* __restrict__ Ga, const float* __restrict__ Gb,
    const float* __restrict__ w2, const float* __restrict__ b2,
    const float* __restrict__ w3, const float* __restrict__ b3,
    const float* __restrict__ w4, const float* __restrict__ b4,
    unsigned short* __restrict__ subjectsA)
{
  __shared__ float sGa[135 * 36];
  __shared__ float sGb[135 * 36];
  __shared__ float sw2[512], sw3[128], sw4[8];
  __shared__ float sb2[16], sb3[8], sb4v[1];

  const int t = threadIdx.x;
  const int b = blockIdx.x >> 5;
  const int c = blockIdx.x & 31;

  for (int i = t; i < 4320; i += 256) {
    const int r = i >> 5, col = i & 31;
    sGa[r * 36 + col] = Ga[b * 4320 + i];
    sGb[r * 36 + col] = Gb[b * 4320 + i];
  }
  for (int i = t; i < 512; i += 256) sw2[i] = w2[i];
  if (t < 128) sw3[t] = w3[t];
  if (t < 8) sw4[t] = w4[t];
  if (t < 16) sb2[t] = b2[t];
  if (t < 8) sb3[t] = b3[t];
  if (t == 0) sb4v[0] = b4[0];
  __syncthreads();

  const int mtile = b >> 4, lrm = b & 15;
  const int pend = min(9045, (c + 1) * 283);
  for (int p = c * 283 + t; p < pend; p += 256) {
    int i = (int)((269.0f - sqrtf((float)(72361 - 8 * p))) * 0.5f);
    i = max(0, min(133, i));
    while (134 * (i + 1) - ((i + 1) * i) / 2 <= p) ++i;
    while (134 * i - (i * (i - 1)) / 2 > p) --i;
    const int j = i + 1 + (p - (134 * i - (i * (i - 1)) / 2));

    float h1[32];
#pragma unroll
    for (int q = 0; q < 8; ++q) {
      const float4 va = *(const float4*)(&sGa[i * 36 + 4 * q]);
      const float4 vb = *(const float4*)(&sGb[j * 36 + 4 * q]);
      h1[4 * q + 0] = fmaxf(va.x + vb.x, 0.f);
      h1[4 * q + 1] = fmaxf(va.y + vb.y, 0.f);
      h1[4 * q + 2] = fmaxf(va.z + vb.z, 0.f);
      h1[4 * q + 3] = fmaxf(va.w + vb.w, 0.f);
    }

    float h2[16];
#pragma unroll
    for (int jj = 0; jj < 16; ++jj) h2[jj] = sb2[jj];
#pragma unroll 8
    for (int ii = 0; ii < 32; ++ii) {
      const float av = h1[ii];
      const float4* wr = reinterpret_cast<const float4*>(&sw2[ii * 16]);
#pragma unroll
      for (int r = 0; r < 4; ++r) {
        float4 w = wr[r];
        h2[4 * r + 0] = fmaf(av, w.x, h2[4 * r + 0]);
        h2[4 * r + 1] = fmaf(av, w.y, h2[4 * r + 1]);
        h2[4 * r + 2] = fmaf(av, w.z, h2[4 * r + 2]);
        h2[4 * r + 3] = fmaf(av, w.w, h2[4 * r + 3]);
      }
    }
#pragma unroll
    for (int jj = 0; jj < 16; ++jj) h2[jj] = fmaxf(h2[jj], 0.f);

    float h3[8];
#pragma unroll
    for (int jj = 0; jj < 8; ++jj) h3[jj] = sb3[jj];
#pragma unroll
    for (int ii = 0; ii < 16; ++ii) {
      const float av = h2[ii];
      const float4* wr = reinterpret_cast<const float4*>(&sw3[ii * 8]);
#pragma unroll
      for (int r = 0; r < 2; ++r) {
        float4 w = wr[r];
        h3[4 * r + 0] = fmaf(av, w.x, h3[4 * r + 0]);
        h3[4 * r + 1] = fmaf(av, w.y, h3[4 * r + 1]);
        h3[4 * r + 2] = fmaf(av, w.z, h3[4 * r + 2]);
        h3[4 * r + 3] = fmaf(av, w.w, h3[4 * r + 3]);
      }
    }
#pragma unroll
    for (int jj = 0; jj < 8; ++jj) h3[jj] = fmaxf(h3[jj], 0.f);

    float z = sb4v[0];
#pragma unroll
    for (int ii = 0; ii < 8; ++ii) z = fmaf(h3[ii], sw4[ii], z);

    const float az = fabsf(z);
    const float e = __expf(-2.f * az);
    const float rr = (1.f - e) / (1.f + e);
    const float val = copysignf(rr, z);

    const int chunk = p >> 5, q8 = (p & 31) >> 3, jj2 = p & 7;
    subjectsA[chunk * 1024 + mtile * 512 + (q8 * 16 + lrm) * 8 + jj2] = f2bf(val);
  }
}

// ---------------------------------------------------------------------------
// c1 (MFMA): C(30x1024) = subjects @ w1. 256 blocks x 4 waves = 1024 jobs.
// ---------------------------------------------------------------------------
__global__ __launch_bounds__(256) void c1_kernel(
    const unsigned short* __restrict__ subjectsA,
    const unsigned short* __restrict__ w1T,
    float* __restrict__ part)
{
  const int t = threadIdx.x;
  const int wv = t >> 6, lane = t & 63, quad = lane >> 4, lr = lane & 15;
  const int job = blockIdx.x * 4 + wv;
  const int ng = job & 15;
  const int kg = job >> 4;
  const int c0 = kg * 5;
  const int cend = min(283, c0 + 5);

  f32x4 acc[2][4] = {};
  for (int ch = c0; ch < cend; ++ch) {
    const bf16x8 a0 = *(const bf16x8*)(subjectsA + ch * 1024 + lane * 8);
    const bf16x8 a1 = *(const bf16x8*)(subjectsA + ch * 1024 + 512 + lane * 8);
#pragma unroll
    for (int nt = 0; nt < 4; ++nt) {
      const int col = (ng * 4 + nt) * 16 + lr;
      const bf16x8 b = *(const bf16x8*)(w1T + (size_t)col * 9088 + ch * 32 + quad * 8);
      acc[0][nt] = __builtin_amdgcn_mfma_f32_16x16x32_bf16(a0, b, acc[0][nt], 0, 0, 0);
      acc[1][nt] = __builtin_amdgcn_mfma_f32_16x16x32_bf16(a1, b, acc[1][nt], 0, 0, 0);
    }
  }
#pragma unroll
  for (int mt = 0; mt < 2; ++mt)
#pragma unroll
    for (int r = 0; r < 4; ++r) {
      const int m = mt * 16 + quad * 4 + r;
      if (m < 30) {
#pragma unroll
        for (int nt = 0; nt < 4; ++nt) {
          const int col = (ng * 4 + nt) * 16 + lr;
          part[(size_t)(m * 64 + kg) * 1024 + col] = acc[mt][nt][r];
        }
      }
    }
}

// ---------------------------------------------------------------------------
// tail_a: reduce 64 partials + rrelu -> act1[30][1024]. 120 blocks.
// ---------------------------------------------------------------------------
__global__ __launch_bounds__(256) void tail_a_kernel(
    const float* __restrict__ part,
    const float* __restrict__ cb1,
    float* __restrict__ act1)
{
  const int r = blockIdx.x >> 2;
  const int cg = blockIdx.x & 3;
  const int j = cg * 256 + threadIdx.x;
  float s = cb1[j];
  const float* pp = part + (size_t)r * 64 * 1024 + j;
#pragma unroll 8
  for (int q = 0; q < 64; ++q) s += pp[q * 1024];
  act1[r * 1024 + j] = s >= 0.f ? s : RRELU_SLOPE * s;
}

// ---------------------------------------------------------------------------
// tail_b: GEMM2 (1024->256) + relu -> act2. 240 blocks.
// ---------------------------------------------------------------------------
__global__ __launch_bounds__(256) void tail_b_kernel(
    const float* __restrict__ act1,
    const float* __restrict__ w2, const float* __restrict__ cb2,
    float* __restrict__ act2)
{
  __shared__ float sa[1024];
  __shared__ float sp[256];
  const int r = blockIdx.x >> 3;
  const int cg = blockIdx.x & 7;
  const int t = threadIdx.x;
  const int c = t & 31;
  const int ks = t >> 5;
  const int col = cg * 32 + c;

  for (int i = t; i < 1024; i += 256) sa[i] = act1[r * 1024 + i];
  __syncthreads();

  float acc = 0.f;
  const int k0 = ks * 128;
  for (int kk = k0; kk < k0 + 128; kk += 4) {
    const float4 a = *reinterpret_cast<const float4*>(&sa[kk]);
    acc = fmaf(a.x, w2[(kk + 0) * 256 + col], acc);
    acc = fmaf(a.y, w2[(kk + 1) * 256 + col], acc);
    acc = fmaf(a.z, w2[(kk + 2) * 256 + col], acc);
    acc = fmaf(a.w, w2[(kk + 3) * 256 + col], acc);
  }
  sp[t] = acc;
  __syncthreads();
  if (t < 32) {
    float s = cb2[col];
#pragma unroll
    for (int q = 0; q < 8; ++q) s += sp[q * 32 + t];
    act2[r * 256 + cg * 32 + t] = fmaxf(s, 0.f);
  }
}

// ---------------------------------------------------------------------------
// tail_c: GEMM3 (256->64, 4-way k-split) + GEMM4 (64->3) + log_softmax.
// ---------------------------------------------------------------------------
__global__ __launch_bounds__(256) void tail_c_kernel(
    const float* __restrict__ act2,
    const float* __restrict__ w3, const float* __restrict__ cb3,
    const float* __restrict__ w4, const float* __restrict__ cb4,
    float* __restrict__ out)
{
  __shared__ float sa[256];
  __shared__ float sp[256];
  __shared__ float sc3[64];
  __shared__ float slg[3];
  const int r = blockIdx.x, t = threadIdx.x;
  const int c = t & 63;
  const int ks = t >> 6;

  sa[t] = act2[r * 256 + t];
  __syncthreads();
  {
    float acc = 0.f;
    const int k0 = ks * 64;
#pragma unroll 4
    for (int kk = k0; kk < k0 + 64; ++kk)
      acc = fmaf(sa[kk], w3[kk * 64 + c], acc);
    sp[t] = acc;
  }
  __syncthreads();
  if (t < 64) {
    const float s = cb3[t] + sp[t] + sp[t + 64] + sp[t + 128] + sp[t + 192];
    sc3[t] = fmaxf(s, 0.f);
  }
  __syncthreads();
  if (t < 3) {
    float acc = cb4[t];
#pragma unroll
    for (int kk = 0; kk < 64; ++kk) acc = fmaf(sc3[kk], w4[kk * 3 + t], acc);
    slg[t] = acc;
  }
  __syncthreads();
  if (t == 0) {
    float m = fmaxf(slg[0], fmaxf(slg[1], slg[2]));
    float se = __expf(slg[0] - m) + __expf(slg[1] - m) + __expf(slg[2] - m);
    float lse = m + logf(se);
    out[r * 3 + 0] = slg[0] - lse;
    out[r * 3 + 1] = slg[1] - lse;
    out[r * 3 + 2] = slg[2] - lse;
  }
}

extern "C" void kernel_launch(void* const* d_in, const int* in_sizes, int n_in,
                              void* d_out, int out_size, void* d_ws, size_t ws_size,
                              hipStream_t stream) {
  const float* x    = (const float*)d_in[0];
  const float* w1c  = (const float*)d_in[1];
  const float* b1c  = (const float*)d_in[2];
  const float* g1   = (const float*)d_in[3];
  const float* bb1  = (const float*)d_in[4];
  const float* w2c  = (const float*)d_in[5];
  const float* b2c  = (const float*)d_in[6];
  const float* g2   = (const float*)d_in[7];
  const float* bb2  = (const float*)d_in[8];
  const float* w3c  = (const float*)d_in[9];
  const float* b3c  = (const float*)d_in[10];
  const float* g3   = (const float*)d_in[11];
  const float* bb3  = (const float*)d_in[12];
  const float* fcw  = (const float*)d_in[13];
  const float* fcb  = (const float*)d_in[14];
  const float* sw1  = (const float*)d_in[15];
  const float* sb1  = (const float*)d_in[16];
  const float* sw2  = (const float*)d_in[17];
  const float* sb2  = (const float*)d_in[18];
  const float* sw3  = (const float*)d_in[19];
  const float* sb3  = (const float*)d_in[20];
  const float* sw4  = (const float*)d_in[21];
  const float* sb4  = (const float*)d_in[22];
  const float* cw1  = (const float*)d_in[23];
  const float* cb1  = (const float*)d_in[24];
  const float* cw2  = (const float*)d_in[25];
  const float* cb2  = (const float*)d_in[26];
  const float* cw3  = (const float*)d_in[27];
  const float* cb3  = (const float*)d_in[28];
  const float* cw4  = (const float*)d_in[29];
  const float* cb4  = (const float*)d_in[30];

  float* ws = (float*)d_ws;
  float* Ga    = ws;                     // 129600
  float* Gb    = ws + 129600;            // -> 259200
  float* part  = ws + 259200;            // 30*64*1024 -> 2225280
  float* bgagb = ws + 2225280;           // 64 -> 2225344
  float* act1  = ws + 2225344;           // 30720 -> 2256064
  float* act2  = ws + 2256064;           // 7680 -> 2263744
  unsigned short* wsu = (unsigned short*)(ws + 2263744);
  unsigned short* w2frag    = wsu;             // 4096 sh
  unsigned short* w3frag    = wsu + 4096;      // -> 13312
  unsigned short* bfragGG   = wsu + 13312;     // -> 152576
  unsigned short* act3      = wsu + 152576;    // -> 8965376
  unsigned short* subjectsA = wsu + 8965376;   // -> 9255168
  unsigned short* w1T       = wsu + 9255168;   // 1024*9088

  setup_kernel<<<2489, 256, 0, stream>>>(w2c, g2, w3c, g3, fcw, fcb, sw1, sb1, cw1,
                                         w2frag, w3frag, bfragGG, bgagb, subjectsA, w1T);
  fe_kernel<<<2025, 128, 0, stream>>>(x, w1c, b1c, g1, bb1, b2c, g2, bb2,
                                      b3c, g3, bb3, w2frag, w3frag, act3);
  gagb_kernel<<<254, 256, 0, stream>>>(act3, bfragGG, bgagb, Ga, Gb);
  sim_kernel<<<960, 256, 0, stream>>>(Ga, Gb, sw2, sb2, sw3, sb3, sw4, sb4, subjectsA);
  c1_kernel<<<256, 256, 0, stream>>>(subjectsA, w1T, part);
  tail_a_kernel<<<120, 256, 0, stream>>>(part, cb1, act1);
  tail_b_kernel<<<240, 256, 0, stream>>>(act1, cw2, cb2, act2);
  tail_c_kernel<<<30, 256, 0, stream>>>(act2, cw3, cb3, cw4, cb4, (float*)d_out);
}